// Round 12
// baseline (331.309 us; speedup 1.0000x reference)
//
#include <hip/hip_runtime.h>
#include <math.h>

#define NFEAT 256
#define NHID 128
#define NCLASS 40
#define BNODES 128
#define BSHIFT 7
#define BCAP 2688
#define MAXBK 1024
#define EPB 16384

typedef unsigned short ushort_t;
typedef unsigned int uint_t;
typedef __attribute__((ext_vector_type(8))) short bf16x8;
typedef __attribute__((ext_vector_type(4))) float f32x4;

static __device__ inline float bf2f(ushort_t u) {
    union { uint_t u; float f; } v; v.u = (uint_t)u << 16; return v.f;
}
static __device__ inline float lo2f(uint_t u) {
    union { uint_t u; float f; } v; v.u = u << 16; return v.f;
}
static __device__ inline float hi2f(uint_t u) {
    union { uint_t u; float f; } v; v.u = u & 0xFFFF0000u; return v.f;
}
static __device__ inline ushort_t f2bf(float f) {
    uint_t u = __float_as_uint(f);
    u += 0x7FFF + ((u >> 16) & 1);           // round-to-nearest-even
    return (ushort_t)(u >> 16);
}
// fused bf16-extract + fp32 accumulate: r = pk.lo*mask.lo + pk.hi*mask.hi + c
static __device__ inline float dot2bf(uint_t pk, uint_t mask, float c) {
    float r;
    asm("v_dot2_f32_bf16 %0, %1, %2, %3" : "=v"(r) : "v"(pk), "v"(mask), "v"(c));
    return r;
}
#define LOMASK 0x00003F80u
#define HIMASK 0x3F800000u

// ---------------- edge partition by dst-bucket: hist / scan / scatter --------

__global__ __launch_bounds__(256) void k_ehist(const int* __restrict__ dst,
                                               int* __restrict__ cnt,
                                               int E, int nbk, int nblk) {
    __shared__ int hist[MAXBK];
    int tid = threadIdx.x, be = blockIdx.x;
    for (int i = tid; i < nbk; i += 256) hist[i] = 0;
    __syncthreads();
    int e0 = be * EPB, e1 = min(e0 + EPB, E);
    for (int e = e0 + tid; e < e1; e += 256)
        atomicAdd(&hist[dst[e] >> BSHIFT], 1);          // LDS int atomic: native
    __syncthreads();
    for (int i = tid; i < nbk; i += 256)
        cnt[(size_t)i * nblk + be] = hist[i];
}

__global__ __launch_bounds__(128) void k_escan(int* __restrict__ cnt,
                                               int* __restrict__ bcnt, int nblk) {
    __shared__ int buf[128];
    int b = blockIdx.x, tid = threadIdx.x;
    int v = (tid < nblk) ? cnt[(size_t)b * nblk + tid] : 0;
    buf[tid] = v;
    __syncthreads();
    for (int off = 1; off < 128; off <<= 1) {
        int t = (tid >= off) ? buf[tid - off] : 0;
        __syncthreads();
        buf[tid] += t;
        __syncthreads();
    }
    if (tid < nblk) cnt[(size_t)b * nblk + tid] = buf[tid] - v;   // exclusive
    if (tid == 127) bcnt[b] = buf[127];                           // total
}

__global__ __launch_bounds__(256) void k_escatter(const int* __restrict__ src,
                                                  const int* __restrict__ dst,
                                                  const int* __restrict__ cnt,
                                                  uint_t* __restrict__ bstore,
                                                  int E, int nbk, int nblk) {
    __shared__ int cur[MAXBK];
    int tid = threadIdx.x, be = blockIdx.x;
    for (int i = tid; i < nbk; i += 256)
        cur[i] = cnt[(size_t)i * nblk + be];
    __syncthreads();
    int e0 = be * EPB, e1 = min(e0 + EPB, E);
    for (int e = e0 + tid; e < e1; e += 256) {
        int d = dst[e];
        int b = d >> BSHIFT;
        int p = atomicAdd(&cur[b], 1);                  // LDS int atomic: native
        if (p < BCAP)
            bstore[(size_t)b * BCAP + p] = ((uint_t)(d & (BNODES - 1)) << 20) | (uint_t)src[e];
    }
}

// ---------------- per-bucket counting sort (LDS), + rp + dinv ----------------

__global__ __launch_bounds__(256) void k_bsort(const uint_t* __restrict__ bstore,
                                               const int* __restrict__ bcnt,
                                               uint_t* __restrict__ colsort,
                                               int* __restrict__ rp,
                                               float* __restrict__ dinv, int N) {
    __shared__ uint_t rec[BCAP];
    __shared__ uint_t srt[BCAP];
    __shared__ int hist[BNODES];
    __shared__ int scan[BNODES];
    __shared__ int cur[BNODES];
    int b = blockIdx.x, tid = threadIdx.x;
    if (tid < BNODES) hist[tid] = 0;
    __syncthreads();
    int cnt = min(bcnt[b], BCAP);
    const uint_t* gp = &bstore[(size_t)b * BCAP];
    for (int e = tid; e < cnt; e += 256) {
        uint_t r = gp[e];
        rec[e] = r;
        atomicAdd(&hist[r >> 20], 1);          // int LDS atomic: native
    }
    __syncthreads();
    if (tid < BNODES) scan[tid] = hist[tid];
    __syncthreads();
    for (int off = 1; off < BNODES; off <<= 1) {
        int v = 0;
        if (tid < BNODES && tid >= off) v = scan[tid - off];
        __syncthreads();
        if (tid < BNODES) scan[tid] += v;
        __syncthreads();
    }
    if (tid < BNODES) cur[tid] = scan[tid] - hist[tid];   // exclusive
    __syncthreads();
    for (int e = tid; e < cnt; e += 256) {
        uint_t r = rec[e];
        int p = atomicAdd(&cur[r >> 20], 1);   // int LDS atomic: native
        srt[p] = r & 0xFFFFF;
    }
    __syncthreads();
    uint_t* cs = &colsort[(size_t)b * BCAP];
    for (int e = tid; e < cnt; e += 256) cs[e] = srt[e];
    if (tid < BNODES) {
        rp[b * (BNODES + 1) + tid] = scan[tid] - hist[tid];
        int n = b * BNODES + tid;
        if (n < N) dinv[n] = rsqrtf((float)hist[tid] + 1.0f);
    }
    if (tid == 0) rp[b * (BNODES + 1) + BNODES] = cnt;
}

// ---------------- weight transpose + hi/lo bf16 split ----------------

__global__ void k_wt(const float* __restrict__ W, ushort_t* __restrict__ Whi,
                     ushort_t* __restrict__ Wlo, int K, int Nw, int Npad) {
    int idx = blockIdx.x * blockDim.x + threadIdx.x;
    if (idx >= Npad * K) return;
    int nrow = idx / K, k = idx - nrow * K;
    float w = (nrow < Nw) ? W[(size_t)k * Nw + nrow] : 0.f;
    ushort_t hi = f2bf(w);
    Whi[idx] = hi;
    Wlo[idx] = f2bf(w - bf2f(hi));
}

// ---------------- MFMA GEMM ----------------
// C = (A @ W) * dinv[row]   (pre-scaled h')
// MODE 0: out slice-major [BNout/32][N][32] bf16 (64B rows) ; MODE 1: row-major [N][NOUT]
// A_FP32: A row-major fp32; else A slice-major bf16 [K/32][N][32]
// BM = 64 or 128; wave w owns rows [w*16*G, +16*G), G = BM/64

template<int K, bool A_FP32, int BM, int BN, int NOUT, int MODE>
__global__ __launch_bounds__(256) void k_gemm_mfma(const void* __restrict__ Ap,
                                                   const ushort_t* __restrict__ Whi,
                                                   const ushort_t* __restrict__ Wlo,
                                                   const float* __restrict__ dinv,
                                                   ushort_t* __restrict__ C, int n) {
    const int BK = 32;
    const int LDA = BK + 8;
    const int G = BM / 64;
    __shared__ ushort_t As[BM][LDA];
    __shared__ ushort_t Bh[BN][LDA];
    __shared__ ushort_t Bl[BN][LDA];
    const int tid = threadIdx.x;
    const int w = tid >> 6, l = tid & 63;
    const int row0 = blockIdx.x * BM;
    const int NJ = BN / 16;
    f32x4 acc[G][NJ] = {};

    for (int k0 = 0; k0 < K; k0 += BK) {
        // stage A tile (BM x 32)
        for (int idx = tid; idx < BM * 4; idx += 256) {
            int r = idx >> 2, c = (idx & 3) * 8;
            if (A_FP32) {
                const float* A = (const float*)Ap;
                float4 v0 = make_float4(0.f, 0.f, 0.f, 0.f);
                float4 v1 = make_float4(0.f, 0.f, 0.f, 0.f);
                if (row0 + r < n) {
                    v0 = *(const float4*)&A[(size_t)(row0 + r) * K + k0 + c];
                    v1 = *(const float4*)&A[(size_t)(row0 + r) * K + k0 + c + 4];
                }
                ushort_t* p = &As[r][c];
                p[0] = f2bf(v0.x); p[1] = f2bf(v0.y); p[2] = f2bf(v0.z); p[3] = f2bf(v0.w);
                p[4] = f2bf(v1.x); p[5] = f2bf(v1.y); p[6] = f2bf(v1.z); p[7] = f2bf(v1.w);
            } else {
                const ushort_t* A = (const ushort_t*)Ap;
                ushort4 v0 = {0, 0, 0, 0}, v1 = {0, 0, 0, 0};
                if (row0 + r < n) {
                    int kk = k0 + c;
                    size_t base = (size_t)(kk >> 5) * n * 32 + (size_t)(row0 + r) * 32 + (kk & 31);
                    v0 = *(const ushort4*)&A[base];
                    v1 = *(const ushort4*)&A[base + 4];
                }
                *(ushort4*)&As[r][c] = v0;
                *(ushort4*)&As[r][c + 4] = v1;
            }
        }
        // stage B tiles (BN x 32, hi + lo)
        for (int idx = tid; idx < BN * 4; idx += 256) {
            int r = idx >> 2, c = (idx & 3) * 8;
            *(ushort4*)&Bh[r][c]     = *(const ushort4*)&Whi[(size_t)r * K + k0 + c];
            *(ushort4*)&Bh[r][c + 4] = *(const ushort4*)&Whi[(size_t)r * K + k0 + c + 4];
            *(ushort4*)&Bl[r][c]     = *(const ushort4*)&Wlo[(size_t)r * K + k0 + c];
            *(ushort4*)&Bl[r][c + 4] = *(const ushort4*)&Wlo[(size_t)r * K + k0 + c + 4];
        }
        __syncthreads();

        const int ko = (l >> 4) * 8;
        bf16x8 a[G];
#pragma unroll
        for (int g = 0; g < G; g++)
            a[g] = *(const bf16x8*)&As[w * 16 * G + g * 16 + (l & 15)][ko];
#pragma unroll
        for (int j = 0; j < NJ; j++) {
            bf16x8 bh = *(const bf16x8*)&Bh[j * 16 + (l & 15)][ko];
            bf16x8 bl = *(const bf16x8*)&Bl[j * 16 + (l & 15)][ko];
#pragma unroll
            for (int g = 0; g < G; g++) {
                acc[g][j] = __builtin_amdgcn_mfma_f32_16x16x32_bf16(a[g], bh, acc[g][j], 0, 0, 0);
                acc[g][j] = __builtin_amdgcn_mfma_f32_16x16x32_bf16(a[g], bl, acc[g][j], 0, 0, 0);
            }
        }
        __syncthreads();
    }

    const int cb = l & 15;
#pragma unroll
    for (int g = 0; g < G; g++) {
        float dnv[4];
#pragma unroll
        for (int r = 0; r < 4; r++) {
            int row = row0 + w * 16 * G + g * 16 + (l >> 4) * 4 + r;
            dnv[r] = (row < n) ? dinv[row] : 0.f;
        }
#pragma unroll
        for (int j = 0; j < NJ; j++) {
#pragma unroll
            for (int r = 0; r < 4; r++) {
                int row = row0 + w * 16 * G + g * 16 + (l >> 4) * 4 + r;
                if (row < n) {
                    float v = dnv[r] * acc[g][j][r];
                    if (MODE == 0)
                        C[(size_t)(j >> 1) * n * 32 + (size_t)row * 32 + (j & 1) * 16 + cb] = f2bf(v);
                    else if (j * 16 + cb < NOUT)
                        C[(size_t)row * NOUT + j * 16 + cb] = f2bf(v);
                }
            }
        }
    }
}

// ---------------- sliced aggregation (layers 1,2) — 64B line rows -----------
// block=(bucket,slice); slice=blk&3; h' [4][N][32] bf16
// 4 lanes/node x uint4 = full 64B line per node per slice; batch-4 gathers

__global__ __launch_bounds__(256) void k_agg_slice(const uint_t* __restrict__ colsort,
                                                   const int* __restrict__ rp,
                                                   const ushort_t* __restrict__ hsl,
                                                   const float* __restrict__ dinv,
                                                   const float* __restrict__ bias,
                                                   ushort_t* __restrict__ out, int N) {
    __shared__ int srp[BNODES + 1];
    __shared__ uint_t cols[BCAP];
    int blk = blockIdx.x;
    int slice = blk & 3, b = blk >> 2;
    int tid = threadIdx.x;
    if (tid <= BNODES) srp[tid] = rp[b * (BNODES + 1) + tid];
    __syncthreads();
    int cnt = srp[BNODES];
    for (int e = tid; e < cnt; e += 256) cols[e] = colsort[(size_t)b * BCAP + e];
    __syncthreads();
    int fq = tid & 3;                  // 16B quarter of the 64B row (8 feats)
    int q  = tid >> 2;                 // node slot 0..63
    const ushort_t* hs = &hsl[(size_t)slice * N * 32 + fq * 8];
    float bv[8];
#pragma unroll
    for (int j = 0; j < 8; j++) bv[j] = bias[slice * 32 + fq * 8 + j];
    for (int nl = q; nl < BNODES; nl += 64) {
        int n = b * BNODES + nl;
        if (n >= N) break;
        int e = srp[nl], e1 = srp[nl + 1];
        uint4 sv = *(const uint4*)&hs[(size_t)n * 32];
        float a[8];
        a[0] = lo2f(sv.x); a[1] = hi2f(sv.x); a[2] = lo2f(sv.y); a[3] = hi2f(sv.y);
        a[4] = lo2f(sv.z); a[5] = hi2f(sv.z); a[6] = lo2f(sv.w); a[7] = hi2f(sv.w);
        for (; e + 4 <= e1; e += 4) {
            uint4 v[4];
#pragma unroll
            for (int i = 0; i < 4; i++) v[i] = *(const uint4*)&hs[(size_t)cols[e + i] * 32];
#pragma unroll
            for (int i = 0; i < 4; i++) {
                a[0] = dot2bf(v[i].x, LOMASK, a[0]); a[1] = dot2bf(v[i].x, HIMASK, a[1]);
                a[2] = dot2bf(v[i].y, LOMASK, a[2]); a[3] = dot2bf(v[i].y, HIMASK, a[3]);
                a[4] = dot2bf(v[i].z, LOMASK, a[4]); a[5] = dot2bf(v[i].z, HIMASK, a[5]);
                a[6] = dot2bf(v[i].w, LOMASK, a[6]); a[7] = dot2bf(v[i].w, HIMASK, a[7]);
            }
        }
        for (; e < e1; e++) {
            uint4 v = *(const uint4*)&hs[(size_t)cols[e] * 32];
            a[0] = dot2bf(v.x, LOMASK, a[0]); a[1] = dot2bf(v.x, HIMASK, a[1]);
            a[2] = dot2bf(v.y, LOMASK, a[2]); a[3] = dot2bf(v.y, HIMASK, a[3]);
            a[4] = dot2bf(v.z, LOMASK, a[4]); a[5] = dot2bf(v.z, HIMASK, a[5]);
            a[6] = dot2bf(v.w, LOMASK, a[6]); a[7] = dot2bf(v.w, HIMASK, a[7]);
        }
        float dn = dinv[n];
        float r[8];
#pragma unroll
        for (int j = 0; j < 8; j++) r[j] = fmaxf(fmaf(dn, a[j], bv[j]), 0.f);
        uint4 o;
        o.x = ((uint_t)f2bf(r[1]) << 16) | f2bf(r[0]);
        o.y = ((uint_t)f2bf(r[3]) << 16) | f2bf(r[2]);
        o.z = ((uint_t)f2bf(r[5]) << 16) | f2bf(r[4]);
        o.w = ((uint_t)f2bf(r[7]) << 16) | f2bf(r[6]);
        *(uint4*)&out[((size_t)slice * N + n) * 32 + fq * 8] = o;
    }
}

// ---------------- layer-3 aggregation + log_softmax — batch-4 ---------------
// h3 row-major [N][40] bf16 pre-scaled; 8-lane groups, 5 active x uint4 (8 feats)

__global__ __launch_bounds__(256) void k_agg40_lsm(const uint_t* __restrict__ colsort,
                                                   const int* __restrict__ rp,
                                                   const ushort_t* __restrict__ h3,
                                                   const float* __restrict__ dinv,
                                                   const float* __restrict__ bias,
                                                   float* __restrict__ out, int N) {
    __shared__ int srp[BNODES + 1];
    __shared__ uint_t cols[BCAP];
    int b = blockIdx.x, tid = threadIdx.x;
    if (tid <= BNODES) srp[tid] = rp[b * (BNODES + 1) + tid];
    __syncthreads();
    int cnt = srp[BNODES];
    for (int e = tid; e < cnt; e += 256) cols[e] = colsort[(size_t)b * BCAP + e];
    __syncthreads();
    int fo = tid & 7;                  // feature octant (8 feats, 16B)
    int g  = tid >> 3;                 // node slot 0..31
    bool act = fo < 5;
    float bv[8];
#pragma unroll
    for (int j = 0; j < 8; j++) bv[j] = act ? bias[fo * 8 + j] : 0.f;
    for (int nl = g; nl < BNODES; nl += 32) {
        int n = b * BNODES + nl;
        if (n >= N) break;
        int e = srp[nl], e1 = srp[nl + 1];
        float a[8] = {0.f, 0.f, 0.f, 0.f, 0.f, 0.f, 0.f, 0.f};
        if (act) {
            uint4 sv = *(const uint4*)&h3[(size_t)n * 40 + fo * 8];
            a[0] = lo2f(sv.x); a[1] = hi2f(sv.x); a[2] = lo2f(sv.y); a[3] = hi2f(sv.y);
            a[4] = lo2f(sv.z); a[5] = hi2f(sv.z); a[6] = lo2f(sv.w); a[7] = hi2f(sv.w);
        }
        for (; e + 4 <= e1; e += 4) {
            if (act) {
                uint4 v[4];
#pragma unroll
                for (int i = 0; i < 4; i++) v[i] = *(const uint4*)&h3[(size_t)cols[e + i] * 40 + fo * 8];
#pragma unroll
                for (int i = 0; i < 4; i++) {
                    a[0] = dot2bf(v[i].x, LOMASK, a[0]); a[1] = dot2bf(v[i].x, HIMASK, a[1]);
                    a[2] = dot2bf(v[i].y, LOMASK, a[2]); a[3] = dot2bf(v[i].y, HIMASK, a[3]);
                    a[4] = dot2bf(v[i].z, LOMASK, a[4]); a[5] = dot2bf(v[i].z, HIMASK, a[5]);
                    a[6] = dot2bf(v[i].w, LOMASK, a[6]); a[7] = dot2bf(v[i].w, HIMASK, a[7]);
                }
            }
        }
        for (; e < e1; e++) {
            if (act) {
                uint4 v = *(const uint4*)&h3[(size_t)cols[e] * 40 + fo * 8];
                a[0] = dot2bf(v.x, LOMASK, a[0]); a[1] = dot2bf(v.x, HIMASK, a[1]);
                a[2] = dot2bf(v.y, LOMASK, a[2]); a[3] = dot2bf(v.y, HIMASK, a[3]);
                a[4] = dot2bf(v.z, LOMASK, a[4]); a[5] = dot2bf(v.z, HIMASK, a[5]);
                a[6] = dot2bf(v.w, LOMASK, a[6]); a[7] = dot2bf(v.w, HIMASK, a[7]);
            }
        }
        float dn = dinv[n];
        float z[8];
        float m = -INFINITY;
#pragma unroll
        for (int j = 0; j < 8; j++) {
            z[j] = act ? fmaf(dn, a[j], bv[j]) : -INFINITY;
            m = fmaxf(m, z[j]);
        }
#pragma unroll
        for (int off = 4; off; off >>= 1) m = fmaxf(m, __shfl_xor(m, off, 8));
        float p = 0.f;
        if (act) {
#pragma unroll
            for (int j = 0; j < 8; j++) p += expf(z[j] - m);
        }
#pragma unroll
        for (int off = 4; off; off >>= 1) p += __shfl_xor(p, off, 8);
        float lse = m + logf(p);
        if (act) {
            float4 o0 = make_float4(z[0] - lse, z[1] - lse, z[2] - lse, z[3] - lse);
            float4 o1 = make_float4(z[4] - lse, z[5] - lse, z[6] - lse, z[7] - lse);
            *(float4*)&out[(size_t)n * NCLASS + fo * 8]     = o0;
            *(float4*)&out[(size_t)n * NCLASS + fo * 8 + 4] = o1;
        }
    }
}

// ---------------- launch ----------------

extern "C" void kernel_launch(void* const* d_in, const int* in_sizes, int n_in,
                              void* d_out, int out_size, void* d_ws, size_t ws_size,
                              hipStream_t stream) {
    const float* x  = (const float*)d_in[0];
    const int*   ei = (const int*)d_in[1];
    const float* W1 = (const float*)d_in[2];
    const float* b1 = (const float*)d_in[3];
    const float* W2 = (const float*)d_in[4];
    const float* b2 = (const float*)d_in[5];
    const float* W3 = (const float*)d_in[6];
    const float* b3 = (const float*)d_in[7];
    float* out = (float*)d_out;
    const int N = in_sizes[0] / NFEAT;
    const int E = in_sizes[1] / 2;
    const int* src = ei;
    const int* dst = ei + E;
    const int NBK = (N + BNODES - 1) / BNODES;
    const int NBLK_E = (E + EPB - 1) / EPB;

    char* ws = (char*)d_ws;
    size_t off = 0;
    auto alloc = [&](size_t bytes) -> void* {
        void* p = ws + off;
        off += (bytes + 255) & ~(size_t)255;
        return p;
    };
    int*      bcnt    = (int*)alloc((size_t)NBK * 4);
    int*      ecnt    = (int*)alloc((size_t)NBK * NBLK_E * 4);
    uint_t*   bstore  = (uint_t*)alloc((size_t)NBK * BCAP * 4);
    uint_t*   colsort = (uint_t*)alloc((size_t)NBK * BCAP * 4);
    int*      rp      = (int*)alloc((size_t)NBK * (BNODES + 1) * 4);
    float*    dinv    = (float*)alloc((size_t)N * 4);
    ushort_t* hsl     = (ushort_t*)alloc((size_t)N * NHID * 2);
    ushort_t* abuf    = (ushort_t*)alloc((size_t)N * NHID * 2);
    ushort_t* h3      = (ushort_t*)alloc((size_t)N * NCLASS * 2);
    ushort_t* Whi1    = (ushort_t*)alloc((size_t)NHID * NFEAT * 2);
    ushort_t* Wlo1    = (ushort_t*)alloc((size_t)NHID * NFEAT * 2);
    ushort_t* Whi2    = (ushort_t*)alloc((size_t)NHID * NHID * 2);
    ushort_t* Wlo2    = (ushort_t*)alloc((size_t)NHID * NHID * 2);
    ushort_t* Whi3    = (ushort_t*)alloc((size_t)48 * NHID * 2);
    ushort_t* Wlo3    = (ushort_t*)alloc((size_t)48 * NHID * 2);
    (void)ws_size; (void)n_in; (void)out_size;

    // weight prep
    k_wt<<<(NHID * NFEAT + 255) / 256, 256, 0, stream>>>(W1, Whi1, Wlo1, NFEAT, NHID, NHID);
    k_wt<<<(NHID * NHID + 255) / 256, 256, 0, stream>>>(W2, Whi2, Wlo2, NHID, NHID, NHID);
    k_wt<<<(48 * NHID + 255) / 256, 256, 0, stream>>>(W3, Whi3, Wlo3, NHID, NCLASS, 48);

    // edge partition (no global atomics) + per-bucket sort + dinv
    k_ehist<<<NBLK_E, 256, 0, stream>>>(dst, ecnt, E, NBK, NBLK_E);
    k_escan<<<NBK, 128, 0, stream>>>(ecnt, bcnt, NBLK_E);
    k_escatter<<<NBLK_E, 256, 0, stream>>>(src, dst, ecnt, bstore, E, NBK, NBLK_E);
    k_bsort<<<NBK, 256, 0, stream>>>(bstore, bcnt, colsort, rp, dinv, N);

    int ngemm128 = (N + 127) / 128;
    int ngemm64  = (N + 63) / 64;
    // layer 1
    k_gemm_mfma<NFEAT, true, 128, 128, 128, 0><<<ngemm128, 256, 0, stream>>>(x, Whi1, Wlo1, dinv, hsl, N);
    k_agg_slice<<<NBK * 4, 256, 0, stream>>>(colsort, rp, hsl, dinv, b1, abuf, N);
    // layer 2
    k_gemm_mfma<NHID, false, 128, 128, 128, 0><<<ngemm128, 256, 0, stream>>>(abuf, Whi2, Wlo2, dinv, hsl, N);
    k_agg_slice<<<NBK * 4, 256, 0, stream>>>(colsort, rp, hsl, dinv, b2, abuf, N);
    // layer 3 + log_softmax
    k_gemm_mfma<NHID, false, 64, 48, NCLASS, 1><<<ngemm64, 256, 0, stream>>>(abuf, Whi3, Wlo3, dinv, h3, N);
    k_agg40_lsm<<<NBK, 256, 0, stream>>>(colsort, rp, h3, dinv, b3, out, N);
}

// Round 13
// 311.696 us; speedup vs baseline: 1.0629x; 1.0629x over previous
//
#include <hip/hip_runtime.h>
#include <math.h>

#define NFEAT 256
#define NHID 128
#define NCLASS 40
#define BNODES 128
#define BSHIFT 7
#define BCAP 2688
#define MAXBK 1024
#define EPB 16384

typedef unsigned short ushort_t;
typedef unsigned int uint_t;
typedef __attribute__((ext_vector_type(8))) short bf16x8;
typedef __attribute__((ext_vector_type(4))) float f32x4;

static __device__ inline float bf2f(ushort_t u) {
    union { uint_t u; float f; } v; v.u = (uint_t)u << 16; return v.f;
}
static __device__ inline float lo2f(uint_t u) {
    union { uint_t u; float f; } v; v.u = u << 16; return v.f;
}
static __device__ inline float hi2f(uint_t u) {
    union { uint_t u; float f; } v; v.u = u & 0xFFFF0000u; return v.f;
}
static __device__ inline ushort_t f2bf(float f) {
    uint_t u = __float_as_uint(f);
    u += 0x7FFF + ((u >> 16) & 1);           // round-to-nearest-even
    return (ushort_t)(u >> 16);
}
// fused bf16-extract + fp32 accumulate: r = pk.lo*mask.lo + pk.hi*mask.hi + c
static __device__ inline float dot2bf(uint_t pk, uint_t mask, float c) {
    float r;
    asm("v_dot2_f32_bf16 %0, %1, %2, %3" : "=v"(r) : "v"(pk), "v"(mask), "v"(c));
    return r;
}
#define LOMASK 0x00003F80u
#define HIMASK 0x3F800000u

// ---------------- edge partition by dst-bucket: hist / scan / scatter --------

__global__ __launch_bounds__(256) void k_ehist(const int* __restrict__ dst,
                                               int* __restrict__ cnt,
                                               int E, int nbk, int nblk) {
    __shared__ int hist[MAXBK];
    int tid = threadIdx.x, be = blockIdx.x;
    for (int i = tid; i < nbk; i += 256) hist[i] = 0;
    __syncthreads();
    int e0 = be * EPB, e1 = min(e0 + EPB, E);
    for (int e = e0 + tid; e < e1; e += 256)
        atomicAdd(&hist[dst[e] >> BSHIFT], 1);          // LDS int atomic: native
    __syncthreads();
    for (int i = tid; i < nbk; i += 256)
        cnt[(size_t)i * nblk + be] = hist[i];
}

__global__ __launch_bounds__(128) void k_escan(int* __restrict__ cnt,
                                               int* __restrict__ bcnt, int nblk) {
    __shared__ int buf[128];
    int b = blockIdx.x, tid = threadIdx.x;
    int v = (tid < nblk) ? cnt[(size_t)b * nblk + tid] : 0;
    buf[tid] = v;
    __syncthreads();
    for (int off = 1; off < 128; off <<= 1) {
        int t = (tid >= off) ? buf[tid - off] : 0;
        __syncthreads();
        buf[tid] += t;
        __syncthreads();
    }
    if (tid < nblk) cnt[(size_t)b * nblk + tid] = buf[tid] - v;   // exclusive
    if (tid == 127) bcnt[b] = buf[127];                           // total
}

__global__ __launch_bounds__(256) void k_escatter(const int* __restrict__ src,
                                                  const int* __restrict__ dst,
                                                  const int* __restrict__ cnt,
                                                  uint_t* __restrict__ bstore,
                                                  int E, int nbk, int nblk) {
    __shared__ int cur[MAXBK];
    int tid = threadIdx.x, be = blockIdx.x;
    for (int i = tid; i < nbk; i += 256)
        cur[i] = cnt[(size_t)i * nblk + be];
    __syncthreads();
    int e0 = be * EPB, e1 = min(e0 + EPB, E);
    for (int e = e0 + tid; e < e1; e += 256) {
        int d = dst[e];
        int b = d >> BSHIFT;
        int p = atomicAdd(&cur[b], 1);                  // LDS int atomic: native
        if (p < BCAP)
            bstore[(size_t)b * BCAP + p] = ((uint_t)(d & (BNODES - 1)) << 20) | (uint_t)src[e];
    }
}

// ---------------- per-bucket counting sort (LDS), + rp + dinv ----------------

__global__ __launch_bounds__(256) void k_bsort(const uint_t* __restrict__ bstore,
                                               const int* __restrict__ bcnt,
                                               uint_t* __restrict__ colsort,
                                               int* __restrict__ rp,
                                               float* __restrict__ dinv, int N) {
    __shared__ uint_t rec[BCAP];
    __shared__ uint_t srt[BCAP];
    __shared__ int hist[BNODES];
    __shared__ int scan[BNODES];
    __shared__ int cur[BNODES];
    int b = blockIdx.x, tid = threadIdx.x;
    if (tid < BNODES) hist[tid] = 0;
    __syncthreads();
    int cnt = min(bcnt[b], BCAP);
    const uint_t* gp = &bstore[(size_t)b * BCAP];
    for (int e = tid; e < cnt; e += 256) {
        uint_t r = gp[e];
        rec[e] = r;
        atomicAdd(&hist[r >> 20], 1);          // int LDS atomic: native
    }
    __syncthreads();
    if (tid < BNODES) scan[tid] = hist[tid];
    __syncthreads();
    for (int off = 1; off < BNODES; off <<= 1) {
        int v = 0;
        if (tid < BNODES && tid >= off) v = scan[tid - off];
        __syncthreads();
        if (tid < BNODES) scan[tid] += v;
        __syncthreads();
    }
    if (tid < BNODES) cur[tid] = scan[tid] - hist[tid];   // exclusive
    __syncthreads();
    for (int e = tid; e < cnt; e += 256) {
        uint_t r = rec[e];
        int p = atomicAdd(&cur[r >> 20], 1);   // int LDS atomic: native
        srt[p] = r & 0xFFFFF;
    }
    __syncthreads();
    uint_t* cs = &colsort[(size_t)b * BCAP];
    for (int e = tid; e < cnt; e += 256) cs[e] = srt[e];
    if (tid < BNODES) {
        rp[b * (BNODES + 1) + tid] = scan[tid] - hist[tid];
        int n = b * BNODES + tid;
        if (n < N) dinv[n] = rsqrtf((float)hist[tid] + 1.0f);
    }
    if (tid == 0) rp[b * (BNODES + 1) + BNODES] = cnt;
}

// ---------------- weight transpose -> bf16 (hi only) ----------------

__global__ void k_wt(const float* __restrict__ W, ushort_t* __restrict__ Whi,
                     int K, int Nw, int Npad) {
    int idx = blockIdx.x * blockDim.x + threadIdx.x;
    if (idx >= Npad * K) return;
    int nrow = idx / K, k = idx - nrow * K;
    float w = (nrow < Nw) ? W[(size_t)k * Nw + nrow] : 0.f;
    Whi[idx] = f2bf(w);
}

// ---------------- MFMA GEMM (bf16 weights, BM=64, BK=64) ----------------
// C = (A @ W) * dinv[row]   (pre-scaled h')
// MODE 0: out slice-major [BN/32][N][32] bf16 (64B rows) ; MODE 1: row-major [N][NOUT]
// A_FP32: A row-major fp32; else A slice-major bf16 [K/32][N][32]

template<int K, bool A_FP32, int BN, int NOUT, int MODE>
__global__ __launch_bounds__(256) void k_gemm_mfma(const void* __restrict__ Ap,
                                                   const ushort_t* __restrict__ Whi,
                                                   const float* __restrict__ dinv,
                                                   ushort_t* __restrict__ C, int n) {
    const int BM = 64, BK = 64;
    const int LDA = BK + 8;                    // 72 ushorts (2-way bank alias: free)
    __shared__ ushort_t As[BM][LDA];
    __shared__ ushort_t Bh[BN][LDA];
    const int tid = threadIdx.x;
    const int w = tid >> 6, l = tid & 63;
    const int row0 = blockIdx.x * BM;
    const int NJ = BN / 16;
    f32x4 acc[NJ] = {};

    for (int k0 = 0; k0 < K; k0 += BK) {
        // stage A tile (64 x 64): thread -> row tid>>2, cols (tid&3)*16 .. +15
        {
            int r = tid >> 2, c = (tid & 3) * 16;
            if (A_FP32) {
                const float* A = (const float*)Ap;
                ushort_t* p = &As[r][c];
                if (row0 + r < n) {
                    const float* ap = &A[(size_t)(row0 + r) * K + k0 + c];
#pragma unroll
                    for (int q = 0; q < 4; q++) {
                        float4 v = *(const float4*)&ap[q * 4];
                        p[q * 4 + 0] = f2bf(v.x); p[q * 4 + 1] = f2bf(v.y);
                        p[q * 4 + 2] = f2bf(v.z); p[q * 4 + 3] = f2bf(v.w);
                    }
                } else {
#pragma unroll
                    for (int q = 0; q < 16; q++) p[q] = 0;
                }
            } else {
                const ushort_t* A = (const ushort_t*)Ap;
                ushort4 v0 = {0, 0, 0, 0}, v1 = {0, 0, 0, 0};
                if (row0 + r < n) {
                    int kk = k0 + c;           // multiple of 16 -> within one 32-slice
                    size_t base = (size_t)(kk >> 5) * n * 32 + (size_t)(row0 + r) * 32 + (kk & 31);
                    v0 = *(const ushort4*)&A[base];
                    v1 = *(const ushort4*)&A[base + 4];
                }
                *(ushort4*)&As[r][c] = v0;
                *(ushort4*)&As[r][c + 4] = v1;
                ushort4 v2 = {0, 0, 0, 0}, v3 = {0, 0, 0, 0};
                if (row0 + r < n) {
                    int kk = k0 + c + 8;
                    size_t base = (size_t)(kk >> 5) * n * 32 + (size_t)(row0 + r) * 32 + (kk & 31);
                    v2 = *(const ushort4*)&A[base];
                    v3 = *(const ushort4*)&A[base + 4];
                }
                *(ushort4*)&As[r][c + 8] = v2;
                *(ushort4*)&As[r][c + 12] = v3;
            }
        }
        // stage B tile (BN x 64)
        for (int idx = tid; idx < BN * 4; idx += 256) {
            int r = idx >> 2, c = (idx & 3) * 16;
            *(ushort4*)&Bh[r][c]      = *(const ushort4*)&Whi[(size_t)r * K + k0 + c];
            *(ushort4*)&Bh[r][c + 4]  = *(const ushort4*)&Whi[(size_t)r * K + k0 + c + 4];
            *(ushort4*)&Bh[r][c + 8]  = *(const ushort4*)&Whi[(size_t)r * K + k0 + c + 8];
            *(ushort4*)&Bh[r][c + 12] = *(const ushort4*)&Whi[(size_t)r * K + k0 + c + 12];
        }
        __syncthreads();

        const int ko = (l >> 4) * 8;
#pragma unroll
        for (int kh = 0; kh < BK; kh += 32) {
            bf16x8 a = *(const bf16x8*)&As[w * 16 + (l & 15)][kh + ko];
#pragma unroll
            for (int j = 0; j < NJ; j++) {
                bf16x8 bh = *(const bf16x8*)&Bh[j * 16 + (l & 15)][kh + ko];
                acc[j] = __builtin_amdgcn_mfma_f32_16x16x32_bf16(a, bh, acc[j], 0, 0, 0);
            }
        }
        __syncthreads();
    }

    float dnv[4];
#pragma unroll
    for (int r = 0; r < 4; r++) {
        int row = row0 + w * 16 + (l >> 4) * 4 + r;
        dnv[r] = (row < n) ? dinv[row] : 0.f;
    }
    const int cb = l & 15;
#pragma unroll
    for (int j = 0; j < NJ; j++) {
#pragma unroll
        for (int r = 0; r < 4; r++) {
            int row = row0 + w * 16 + (l >> 4) * 4 + r;
            if (row < n) {
                float v = dnv[r] * acc[j][r];
                if (MODE == 0)
                    C[(size_t)(j >> 1) * n * 32 + (size_t)row * 32 + (j & 1) * 16 + cb] = f2bf(v);
                else if (j * 16 + cb < NOUT)
                    C[(size_t)row * NOUT + j * 16 + cb] = f2bf(v);
            }
        }
    }
}

// ---------------- sliced aggregation (layers 1,2) — 64B line rows -----------
// block=(bucket,slice); slice=blk&3; h' [4][N][32] bf16
// 4 lanes/node x uint4 = full 64B line per node per slice; batch-4 gathers

__global__ __launch_bounds__(256) void k_agg_slice(const uint_t* __restrict__ colsort,
                                                   const int* __restrict__ rp,
                                                   const ushort_t* __restrict__ hsl,
                                                   const float* __restrict__ dinv,
                                                   const float* __restrict__ bias,
                                                   ushort_t* __restrict__ out, int N) {
    __shared__ int srp[BNODES + 1];
    __shared__ uint_t cols[BCAP];
    int blk = blockIdx.x;
    int slice = blk & 3, b = blk >> 2;
    int tid = threadIdx.x;
    if (tid <= BNODES) srp[tid] = rp[b * (BNODES + 1) + tid];
    __syncthreads();
    int cnt = srp[BNODES];
    for (int e = tid; e < cnt; e += 256) cols[e] = colsort[(size_t)b * BCAP + e];
    __syncthreads();
    int fq = tid & 3;                  // 16B quarter of the 64B row (8 feats)
    int q  = tid >> 2;                 // node slot 0..63
    const ushort_t* hs = &hsl[(size_t)slice * N * 32 + fq * 8];
    float bv[8];
#pragma unroll
    for (int j = 0; j < 8; j++) bv[j] = bias[slice * 32 + fq * 8 + j];
    for (int nl = q; nl < BNODES; nl += 64) {
        int n = b * BNODES + nl;
        if (n >= N) break;
        int e = srp[nl], e1 = srp[nl + 1];
        uint4 sv = *(const uint4*)&hs[(size_t)n * 32];
        float a[8];
        a[0] = lo2f(sv.x); a[1] = hi2f(sv.x); a[2] = lo2f(sv.y); a[3] = hi2f(sv.y);
        a[4] = lo2f(sv.z); a[5] = hi2f(sv.z); a[6] = lo2f(sv.w); a[7] = hi2f(sv.w);
        for (; e + 4 <= e1; e += 4) {
            uint4 v[4];
#pragma unroll
            for (int i = 0; i < 4; i++) v[i] = *(const uint4*)&hs[(size_t)cols[e + i] * 32];
#pragma unroll
            for (int i = 0; i < 4; i++) {
                a[0] = dot2bf(v[i].x, LOMASK, a[0]); a[1] = dot2bf(v[i].x, HIMASK, a[1]);
                a[2] = dot2bf(v[i].y, LOMASK, a[2]); a[3] = dot2bf(v[i].y, HIMASK, a[3]);
                a[4] = dot2bf(v[i].z, LOMASK, a[4]); a[5] = dot2bf(v[i].z, HIMASK, a[5]);
                a[6] = dot2bf(v[i].w, LOMASK, a[6]); a[7] = dot2bf(v[i].w, HIMASK, a[7]);
            }
        }
        for (; e < e1; e++) {
            uint4 v = *(const uint4*)&hs[(size_t)cols[e] * 32];
            a[0] = dot2bf(v.x, LOMASK, a[0]); a[1] = dot2bf(v.x, HIMASK, a[1]);
            a[2] = dot2bf(v.y, LOMASK, a[2]); a[3] = dot2bf(v.y, HIMASK, a[3]);
            a[4] = dot2bf(v.z, LOMASK, a[4]); a[5] = dot2bf(v.z, HIMASK, a[5]);
            a[6] = dot2bf(v.w, LOMASK, a[6]); a[7] = dot2bf(v.w, HIMASK, a[7]);
        }
        float dn = dinv[n];
        float r[8];
#pragma unroll
        for (int j = 0; j < 8; j++) r[j] = fmaxf(fmaf(dn, a[j], bv[j]), 0.f);
        uint4 o;
        o.x = ((uint_t)f2bf(r[1]) << 16) | f2bf(r[0]);
        o.y = ((uint_t)f2bf(r[3]) << 16) | f2bf(r[2]);
        o.z = ((uint_t)f2bf(r[5]) << 16) | f2bf(r[4]);
        o.w = ((uint_t)f2bf(r[7]) << 16) | f2bf(r[6]);
        *(uint4*)&out[((size_t)slice * N + n) * 32 + fq * 8] = o;
    }
}

// ---------------- layer-3 aggregation + log_softmax — batch-4 ---------------
// h3 row-major [N][40] bf16 pre-scaled; 8-lane groups, 5 active x uint4 (8 feats)

__global__ __launch_bounds__(256) void k_agg40_lsm(const uint_t* __restrict__ colsort,
                                                   const int* __restrict__ rp,
                                                   const ushort_t* __restrict__ h3,
                                                   const float* __restrict__ dinv,
                                                   const float* __restrict__ bias,
                                                   float* __restrict__ out, int N) {
    __shared__ int srp[BNODES + 1];
    __shared__ uint_t cols[BCAP];
    int b = blockIdx.x, tid = threadIdx.x;
    if (tid <= BNODES) srp[tid] = rp[b * (BNODES + 1) + tid];
    __syncthreads();
    int cnt = srp[BNODES];
    for (int e = tid; e < cnt; e += 256) cols[e] = colsort[(size_t)b * BCAP + e];
    __syncthreads();
    int fo = tid & 7;                  // feature octant (8 feats, 16B)
    int g  = tid >> 3;                 // node slot 0..31
    bool act = fo < 5;
    float bv[8];
#pragma unroll
    for (int j = 0; j < 8; j++) bv[j] = act ? bias[fo * 8 + j] : 0.f;
    for (int nl = g; nl < BNODES; nl += 32) {
        int n = b * BNODES + nl;
        if (n >= N) break;
        int e = srp[nl], e1 = srp[nl + 1];
        float a[8] = {0.f, 0.f, 0.f, 0.f, 0.f, 0.f, 0.f, 0.f};
        if (act) {
            uint4 sv = *(const uint4*)&h3[(size_t)n * 40 + fo * 8];
            a[0] = lo2f(sv.x); a[1] = hi2f(sv.x); a[2] = lo2f(sv.y); a[3] = hi2f(sv.y);
            a[4] = lo2f(sv.z); a[5] = hi2f(sv.z); a[6] = lo2f(sv.w); a[7] = hi2f(sv.w);
        }
        for (; e + 4 <= e1; e += 4) {
            if (act) {
                uint4 v[4];
#pragma unroll
                for (int i = 0; i < 4; i++) v[i] = *(const uint4*)&h3[(size_t)cols[e + i] * 40 + fo * 8];
#pragma unroll
                for (int i = 0; i < 4; i++) {
                    a[0] = dot2bf(v[i].x, LOMASK, a[0]); a[1] = dot2bf(v[i].x, HIMASK, a[1]);
                    a[2] = dot2bf(v[i].y, LOMASK, a[2]); a[3] = dot2bf(v[i].y, HIMASK, a[3]);
                    a[4] = dot2bf(v[i].z, LOMASK, a[4]); a[5] = dot2bf(v[i].z, HIMASK, a[5]);
                    a[6] = dot2bf(v[i].w, LOMASK, a[6]); a[7] = dot2bf(v[i].w, HIMASK, a[7]);
                }
            }
        }
        for (; e < e1; e++) {
            if (act) {
                uint4 v = *(const uint4*)&h3[(size_t)cols[e] * 40 + fo * 8];
                a[0] = dot2bf(v.x, LOMASK, a[0]); a[1] = dot2bf(v.x, HIMASK, a[1]);
                a[2] = dot2bf(v.y, LOMASK, a[2]); a[3] = dot2bf(v.y, HIMASK, a[3]);
                a[4] = dot2bf(v.z, LOMASK, a[4]); a[5] = dot2bf(v.z, HIMASK, a[5]);
                a[6] = dot2bf(v.w, LOMASK, a[6]); a[7] = dot2bf(v.w, HIMASK, a[7]);
            }
        }
        float dn = dinv[n];
        float z[8];
        float m = -INFINITY;
#pragma unroll
        for (int j = 0; j < 8; j++) {
            z[j] = act ? fmaf(dn, a[j], bv[j]) : -INFINITY;
            m = fmaxf(m, z[j]);
        }
#pragma unroll
        for (int off = 4; off; off >>= 1) m = fmaxf(m, __shfl_xor(m, off, 8));
        float p = 0.f;
        if (act) {
#pragma unroll
            for (int j = 0; j < 8; j++) p += expf(z[j] - m);
        }
#pragma unroll
        for (int off = 4; off; off >>= 1) p += __shfl_xor(p, off, 8);
        float lse = m + logf(p);
        if (act) {
            float4 o0 = make_float4(z[0] - lse, z[1] - lse, z[2] - lse, z[3] - lse);
            float4 o1 = make_float4(z[4] - lse, z[5] - lse, z[6] - lse, z[7] - lse);
            *(float4*)&out[(size_t)n * NCLASS + fo * 8]     = o0;
            *(float4*)&out[(size_t)n * NCLASS + fo * 8 + 4] = o1;
        }
    }
}

// ---------------- launch ----------------

extern "C" void kernel_launch(void* const* d_in, const int* in_sizes, int n_in,
                              void* d_out, int out_size, void* d_ws, size_t ws_size,
                              hipStream_t stream) {
    const float* x  = (const float*)d_in[0];
    const int*   ei = (const int*)d_in[1];
    const float* W1 = (const float*)d_in[2];
    const float* b1 = (const float*)d_in[3];
    const float* W2 = (const float*)d_in[4];
    const float* b2 = (const float*)d_in[5];
    const float* W3 = (const float*)d_in[6];
    const float* b3 = (const float*)d_in[7];
    float* out = (float*)d_out;
    const int N = in_sizes[0] / NFEAT;
    const int E = in_sizes[1] / 2;
    const int* src = ei;
    const int* dst = ei + E;
    const int NBK = (N + BNODES - 1) / BNODES;
    const int NBLK_E = (E + EPB - 1) / EPB;

    char* ws = (char*)d_ws;
    size_t off = 0;
    auto alloc = [&](size_t bytes) -> void* {
        void* p = ws + off;
        off += (bytes + 255) & ~(size_t)255;
        return p;
    };
    int*      bcnt    = (int*)alloc((size_t)NBK * 4);
    int*      ecnt    = (int*)alloc((size_t)NBK * NBLK_E * 4);
    uint_t*   bstore  = (uint_t*)alloc((size_t)NBK * BCAP * 4);
    uint_t*   colsort = (uint_t*)alloc((size_t)NBK * BCAP * 4);
    int*      rp      = (int*)alloc((size_t)NBK * (BNODES + 1) * 4);
    float*    dinv    = (float*)alloc((size_t)N * 4);
    ushort_t* hsl     = (ushort_t*)alloc((size_t)N * NHID * 2);
    ushort_t* abuf    = (ushort_t*)alloc((size_t)N * NHID * 2);
    ushort_t* h3      = (ushort_t*)alloc((size_t)N * NCLASS * 2);
    ushort_t* Whi1    = (ushort_t*)alloc((size_t)NHID * NFEAT * 2);
    ushort_t* Whi2    = (ushort_t*)alloc((size_t)NHID * NHID * 2);
    ushort_t* Whi3    = (ushort_t*)alloc((size_t)48 * NHID * 2);
    (void)ws_size; (void)n_in; (void)out_size;

    // weight prep (bf16 transpose, hi only)
    k_wt<<<(NHID * NFEAT + 255) / 256, 256, 0, stream>>>(W1, Whi1, NFEAT, NHID, NHID);
    k_wt<<<(NHID * NHID + 255) / 256, 256, 0, stream>>>(W2, Whi2, NHID, NHID, NHID);
    k_wt<<<(48 * NHID + 255) / 256, 256, 0, stream>>>(W3, Whi3, NHID, NCLASS, 48);

    // edge partition (no global atomics) + per-bucket sort + dinv
    k_ehist<<<NBLK_E, 256, 0, stream>>>(dst, ecnt, E, NBK, NBLK_E);
    k_escan<<<NBK, 128, 0, stream>>>(ecnt, bcnt, NBLK_E);
    k_escatter<<<NBLK_E, 256, 0, stream>>>(src, dst, ecnt, bstore, E, NBK, NBLK_E);
    k_bsort<<<NBK, 256, 0, stream>>>(bstore, bcnt, colsort, rp, dinv, N);

    int ngemm = (N + 63) / 64;
    // layer 1
    k_gemm_mfma<NFEAT, true, 128, 128, 0><<<ngemm, 256, 0, stream>>>(x, Whi1, dinv, hsl, N);
    k_agg_slice<<<NBK * 4, 256, 0, stream>>>(colsort, rp, hsl, dinv, b1, abuf, N);
    // layer 2
    k_gemm_mfma<NHID, false, 128, 128, 0><<<ngemm, 256, 0, stream>>>(abuf, Whi2, dinv, hsl, N);
    k_agg_slice<<<NBK * 4, 256, 0, stream>>>(colsort, rp, hsl, dinv, b2, abuf, N);
    // layer 3 + log_softmax
    k_gemm_mfma<NHID, false, 48, NCLASS, 1><<<ngemm, 256, 0, stream>>>(abuf, Whi3, dinv, h3, N);
    k_agg40_lsm<<<NBK, 256, 0, stream>>>(colsort, rp, h3, dinv, b3, out, N);
}

// Round 14
// 292.879 us; speedup vs baseline: 1.1312x; 1.0643x over previous
//
#include <hip/hip_runtime.h>
#include <math.h>

#define NFEAT 256
#define NHID 128
#define NCLASS 40
#define BNODES 128
#define BSHIFT 7
#define BCAP 2688
#define MAXBK 1024
#define EPB 16384

typedef unsigned short ushort_t;
typedef unsigned int uint_t;
typedef __attribute__((ext_vector_type(8))) short bf16x8;
typedef __attribute__((ext_vector_type(4))) float f32x4;

static __device__ inline float bf2f(ushort_t u) {
    union { uint_t u; float f; } v; v.u = (uint_t)u << 16; return v.f;
}
static __device__ inline float lo2f(uint_t u) {
    union { uint_t u; float f; } v; v.u = u << 16; return v.f;
}
static __device__ inline float hi2f(uint_t u) {
    union { uint_t u; float f; } v; v.u = u & 0xFFFF0000u; return v.f;
}
static __device__ inline ushort_t f2bf(float f) {
    uint_t u = __float_as_uint(f);
    u += 0x7FFF + ((u >> 16) & 1);           // round-to-nearest-even
    return (ushort_t)(u >> 16);
}
// fused bf16-extract + fp32 accumulate
static __device__ inline float dot2bf(uint_t pk, uint_t mask, float c) {
    float r;
    asm("v_dot2_f32_bf16 %0, %1, %2, %3" : "=v"(r) : "v"(pk), "v"(mask), "v"(c));
    return r;
}
#define LOMASK 0x00003F80u
#define HIMASK 0x3F800000u

// async global->LDS 16B (dest = wave-uniform base + lane*16)
static __device__ __forceinline__ void gload16(const void* g, void* l) {
    __builtin_amdgcn_global_load_lds(
        (const __attribute__((address_space(1))) uint_t*)g,
        (__attribute__((address_space(3))) uint_t*)l, 16, 0, 0);
}

// ---------------- edge partition by dst-bucket: hist / scan / scatter --------

__global__ __launch_bounds__(256) void k_ehist(const int* __restrict__ dst,
                                               int* __restrict__ cnt,
                                               int E, int nbk, int nblk) {
    __shared__ int hist[MAXBK];
    int tid = threadIdx.x, be = blockIdx.x;
    for (int i = tid; i < nbk; i += 256) hist[i] = 0;
    __syncthreads();
    int e0 = be * EPB, e1 = min(e0 + EPB, E);
    for (int e = e0 + tid; e < e1; e += 256)
        atomicAdd(&hist[dst[e] >> BSHIFT], 1);          // LDS int atomic: native
    __syncthreads();
    for (int i = tid; i < nbk; i += 256)
        cnt[(size_t)i * nblk + be] = hist[i];
}

__global__ __launch_bounds__(128) void k_escan(int* __restrict__ cnt,
                                               int* __restrict__ bcnt, int nblk) {
    __shared__ int buf[128];
    int b = blockIdx.x, tid = threadIdx.x;
    int v = (tid < nblk) ? cnt[(size_t)b * nblk + tid] : 0;
    buf[tid] = v;
    __syncthreads();
    for (int off = 1; off < 128; off <<= 1) {
        int t = (tid >= off) ? buf[tid - off] : 0;
        __syncthreads();
        buf[tid] += t;
        __syncthreads();
    }
    if (tid < nblk) cnt[(size_t)b * nblk + tid] = buf[tid] - v;   // exclusive
    if (tid == 127) bcnt[b] = buf[127];                           // total
}

__global__ __launch_bounds__(256) void k_escatter(const int* __restrict__ src,
                                                  const int* __restrict__ dst,
                                                  const int* __restrict__ cnt,
                                                  uint_t* __restrict__ bstore,
                                                  int E, int nbk, int nblk) {
    __shared__ int cur[MAXBK];
    int tid = threadIdx.x, be = blockIdx.x;
    for (int i = tid; i < nbk; i += 256)
        cur[i] = cnt[(size_t)i * nblk + be];
    __syncthreads();
    int e0 = be * EPB, e1 = min(e0 + EPB, E);
    for (int e = e0 + tid; e < e1; e += 256) {
        int d = dst[e];
        int b = d >> BSHIFT;
        int p = atomicAdd(&cur[b], 1);                  // LDS int atomic: native
        if (p < BCAP)
            bstore[(size_t)b * BCAP + p] = ((uint_t)(d & (BNODES - 1)) << 20) | (uint_t)src[e];
    }
}

// ---------------- per-bucket counting sort (LDS), + rp + dinv ----------------

__global__ __launch_bounds__(256) void k_bsort(const uint_t* __restrict__ bstore,
                                               const int* __restrict__ bcnt,
                                               uint_t* __restrict__ colsort,
                                               int* __restrict__ rp,
                                               float* __restrict__ dinv, int N) {
    __shared__ uint_t rec[BCAP];
    __shared__ uint_t srt[BCAP];
    __shared__ int hist[BNODES];
    __shared__ int scan[BNODES];
    __shared__ int cur[BNODES];
    int b = blockIdx.x, tid = threadIdx.x;
    if (tid < BNODES) hist[tid] = 0;
    __syncthreads();
    int cnt = min(bcnt[b], BCAP);
    const uint_t* gp = &bstore[(size_t)b * BCAP];
    for (int e = tid; e < cnt; e += 256) {
        uint_t r = gp[e];
        rec[e] = r;
        atomicAdd(&hist[r >> 20], 1);          // int LDS atomic: native
    }
    __syncthreads();
    if (tid < BNODES) scan[tid] = hist[tid];
    __syncthreads();
    for (int off = 1; off < BNODES; off <<= 1) {
        int v = 0;
        if (tid < BNODES && tid >= off) v = scan[tid - off];
        __syncthreads();
        if (tid < BNODES) scan[tid] += v;
        __syncthreads();
    }
    if (tid < BNODES) cur[tid] = scan[tid] - hist[tid];   // exclusive
    __syncthreads();
    for (int e = tid; e < cnt; e += 256) {
        uint_t r = rec[e];
        int p = atomicAdd(&cur[r >> 20], 1);   // int LDS atomic: native
        srt[p] = r & 0xFFFFF;
    }
    __syncthreads();
    uint_t* cs = &colsort[(size_t)b * BCAP];
    for (int e = tid; e < cnt; e += 256) cs[e] = srt[e];
    if (tid < BNODES) {
        rp[b * (BNODES + 1) + tid] = scan[tid] - hist[tid];
        int n = b * BNODES + tid;
        if (n < N) dinv[n] = rsqrtf((float)hist[tid] + 1.0f);
    }
    if (tid == 0) rp[b * (BNODES + 1) + BNODES] = cnt;
}

// ---------------- fused weight transpose -> bf16 (W3 padded to 64 rows) -----

__global__ __launch_bounds__(256) void k_wtall(const float* __restrict__ W1,
                                               const float* __restrict__ W2,
                                               const float* __restrict__ W3,
                                               ushort_t* __restrict__ T1,
                                               ushort_t* __restrict__ T2,
                                               ushort_t* __restrict__ T3) {
    int idx = blockIdx.x * 256 + threadIdx.x;
    if (idx < NHID * NFEAT) {                                // T1[128][256]
        int nrow = idx >> 8, k = idx & 255;
        T1[idx] = f2bf(W1[(size_t)k * NHID + nrow]);
    } else if ((idx -= NHID * NFEAT) < NHID * NHID) {        // T2[128][128]
        int nrow = idx >> 7, k = idx & 127;
        T2[idx] = f2bf(W2[(size_t)k * NHID + nrow]);
    } else if ((idx -= NHID * NHID) < 64 * NHID) {           // T3[64][128], pad
        int nrow = idx >> 7, k = idx & 127;
        T3[idx] = f2bf(nrow < NCLASS ? W3[(size_t)k * NCLASS + nrow] : 0.f);
    }
}

// ---------------- MFMA GEMM (bf16 weights, BM=64, BK=64, async LDS stage) ----
// C = (A @ W) * dinv[row]   (pre-scaled h')
// LDS tiles unpadded [rows][64] with chunk swizzle phys = q ^ (row&7)
// (16B chunks; inverse-swizzle applied on per-lane global SOURCE address)
// MODE 0: out slice-major [BN/32][N][32] bf16 (64B rows); MODE 1: row-major [N][OST]
// A_FP32: A row-major fp32 (convert path); else A slice-major bf16 [K/32][N][32]

template<int K, bool A_FP32, int BN, int OST, int MODE>
__global__ __launch_bounds__(256) void k_gemm_mfma(const void* __restrict__ Ap,
                                                   const ushort_t* __restrict__ Whi,
                                                   const float* __restrict__ dinv,
                                                   ushort_t* __restrict__ C, int n) {
    const int BM = 64, BK = 64;
    __shared__ ushort_t As[BM * BK];
    __shared__ ushort_t Bh[BN * BK];
    const int tid = threadIdx.x;
    const int w = tid >> 6, l = tid & 63;
    const int row0 = blockIdx.x * BM;
    const int NJ = BN / 16;
    f32x4 acc[NJ] = {};

    for (int k0 = 0; k0 < K; k0 += BK) {
        // ---- stage A tile (64 x 64) ----
        if (A_FP32) {
            // convert path: thread r=tid>>2 covers logical chunks q=2*(tid&3), +1
            int r = tid >> 2;
            if (row0 + r < n) {
                const float* A = (const float*)Ap;
                const float* ap = &A[(size_t)(row0 + r) * K + k0];
#pragma unroll
                for (int h = 0; h < 2; h++) {
                    int q = (tid & 3) * 2 + h;
                    float4 v0 = *(const float4*)&ap[q * 8];
                    float4 v1 = *(const float4*)&ap[q * 8 + 4];
                    ushort4 o0, o1;
                    o0.x = f2bf(v0.x); o0.y = f2bf(v0.y); o0.z = f2bf(v0.z); o0.w = f2bf(v0.w);
                    o1.x = f2bf(v1.x); o1.y = f2bf(v1.y); o1.z = f2bf(v1.z); o1.w = f2bf(v1.w);
                    int pc = q ^ (r & 7);
                    *(ushort4*)&As[r * 64 + pc * 8]     = o0;
                    *(ushort4*)&As[r * 64 + pc * 8 + 4] = o1;
                }
            }
        } else {
            // async path: 512 chunks, 2 rounds of 256 lanes
            const ushort_t* A = (const ushort_t*)Ap;
#pragma unroll
            for (int m = 0; m < 2; m++) {
                int unit = m * 256 + tid;
                int r = unit >> 3, pc = unit & 7;
                int lc = pc ^ (r & 7);
                int kk = k0 + lc * 8;
                size_t rowg = (size_t)min(row0 + r, n - 1);   // clamp: junk rows unused
                const ushort_t* src = &A[(size_t)(kk >> 5) * n * 32 + rowg * 32 + (kk & 31)];
                gload16(src, &As[(size_t)unit * 8]);
            }
        }
        // ---- stage B tile (BN x 64): BN*8 chunks, BN/32 rounds ----
#pragma unroll
        for (int m = 0; m < BN / 32; m++) {
            int unit = m * 256 + tid;
            int r = unit >> 3, pc = unit & 7;
            int lc = pc ^ (r & 7);
            gload16(&Whi[(size_t)r * K + k0 + lc * 8], &Bh[(size_t)unit * 8]);
        }
        __syncthreads();   // drains vmcnt (global_load_lds) + lgkmcnt (ds_write)

        const int lo4 = l & 15;
        const int swz = l & 7;
#pragma unroll
        for (int kh = 0; kh < BK; kh += 32) {
            int q = (kh >> 3) + (l >> 4);
            int ra = w * 16 + lo4;
            bf16x8 a = *(const bf16x8*)&As[ra * 64 + (q ^ swz) * 8];
#pragma unroll
            for (int j = 0; j < NJ; j++) {
                int rb = j * 16 + lo4;
                bf16x8 bh = *(const bf16x8*)&Bh[rb * 64 + (q ^ swz) * 8];
                acc[j] = __builtin_amdgcn_mfma_f32_16x16x32_bf16(a, bh, acc[j], 0, 0, 0);
            }
        }
        __syncthreads();
    }

    float dnv[4];
#pragma unroll
    for (int r = 0; r < 4; r++) {
        int row = row0 + w * 16 + (l >> 4) * 4 + r;
        dnv[r] = (row < n) ? dinv[row] : 0.f;
    }
    const int cb = l & 15;
#pragma unroll
    for (int j = 0; j < NJ; j++) {
#pragma unroll
        for (int r = 0; r < 4; r++) {
            int row = row0 + w * 16 + (l >> 4) * 4 + r;
            if (row < n) {
                float v = dnv[r] * acc[j][r];
                if (MODE == 0)
                    C[(size_t)(j >> 1) * n * 32 + (size_t)row * 32 + (j & 1) * 16 + cb] = f2bf(v);
                else
                    C[(size_t)row * OST + j * 16 + cb] = f2bf(v);
            }
        }
    }
}

// ---------------- sliced aggregation (layers 1,2) — 64B line rows -----------
// block=(bucket,slice); slice=blk&3; h' [4][N][32] bf16
// 4 lanes/node x uint4 = full 64B line per node per slice; batch-4 gathers

__global__ __launch_bounds__(256) void k_agg_slice(const uint_t* __restrict__ colsort,
                                                   const int* __restrict__ rp,
                                                   const ushort_t* __restrict__ hsl,
                                                   const float* __restrict__ dinv,
                                                   const float* __restrict__ bias,
                                                   ushort_t* __restrict__ out, int N) {
    __shared__ int srp[BNODES + 1];
    __shared__ uint_t cols[BCAP];
    int blk = blockIdx.x;
    int slice = blk & 3, b = blk >> 2;
    int tid = threadIdx.x;
    if (tid <= BNODES) srp[tid] = rp[b * (BNODES + 1) + tid];
    __syncthreads();
    int cnt = srp[BNODES];
    for (int e = tid; e < cnt; e += 256) cols[e] = colsort[(size_t)b * BCAP + e];
    __syncthreads();
    int fq = tid & 3;                  // 16B quarter of the 64B row (8 feats)
    int q  = tid >> 2;                 // node slot 0..63
    const ushort_t* hs = &hsl[(size_t)slice * N * 32 + fq * 8];
    float bv[8];
#pragma unroll
    for (int j = 0; j < 8; j++) bv[j] = bias[slice * 32 + fq * 8 + j];
    for (int nl = q; nl < BNODES; nl += 64) {
        int n = b * BNODES + nl;
        if (n >= N) break;
        int e = srp[nl], e1 = srp[nl + 1];
        uint4 sv = *(const uint4*)&hs[(size_t)n * 32];
        float a[8];
        a[0] = lo2f(sv.x); a[1] = hi2f(sv.x); a[2] = lo2f(sv.y); a[3] = hi2f(sv.y);
        a[4] = lo2f(sv.z); a[5] = hi2f(sv.z); a[6] = lo2f(sv.w); a[7] = hi2f(sv.w);
        for (; e + 4 <= e1; e += 4) {
            uint4 v[4];
#pragma unroll
            for (int i = 0; i < 4; i++) v[i] = *(const uint4*)&hs[(size_t)cols[e + i] * 32];
#pragma unroll
            for (int i = 0; i < 4; i++) {
                a[0] = dot2bf(v[i].x, LOMASK, a[0]); a[1] = dot2bf(v[i].x, HIMASK, a[1]);
                a[2] = dot2bf(v[i].y, LOMASK, a[2]); a[3] = dot2bf(v[i].y, HIMASK, a[3]);
                a[4] = dot2bf(v[i].z, LOMASK, a[4]); a[5] = dot2bf(v[i].z, HIMASK, a[5]);
                a[6] = dot2bf(v[i].w, LOMASK, a[6]); a[7] = dot2bf(v[i].w, HIMASK, a[7]);
            }
        }
        for (; e < e1; e++) {
            uint4 v = *(const uint4*)&hs[(size_t)cols[e] * 32];
            a[0] = dot2bf(v.x, LOMASK, a[0]); a[1] = dot2bf(v.x, HIMASK, a[1]);
            a[2] = dot2bf(v.y, LOMASK, a[2]); a[3] = dot2bf(v.y, HIMASK, a[3]);
            a[4] = dot2bf(v.z, LOMASK, a[4]); a[5] = dot2bf(v.z, HIMASK, a[5]);
            a[6] = dot2bf(v.w, LOMASK, a[6]); a[7] = dot2bf(v.w, HIMASK, a[7]);
        }
        float dn = dinv[n];
        float r[8];
#pragma unroll
        for (int j = 0; j < 8; j++) r[j] = fmaxf(fmaf(dn, a[j], bv[j]), 0.f);
        uint4 o;
        o.x = ((uint_t)f2bf(r[1]) << 16) | f2bf(r[0]);
        o.y = ((uint_t)f2bf(r[3]) << 16) | f2bf(r[2]);
        o.z = ((uint_t)f2bf(r[5]) << 16) | f2bf(r[4]);
        o.w = ((uint_t)f2bf(r[7]) << 16) | f2bf(r[6]);
        *(uint4*)&out[((size_t)slice * N + n) * 32 + fq * 8] = o;
    }
}

// ---------------- layer-3 aggregation + log_softmax — padded 128B rows ------
// h3 row-major [N][64] bf16 pre-scaled (cols >= 40 junk, never read)

__global__ __launch_bounds__(256) void k_agg40_lsm(const uint_t* __restrict__ colsort,
                                                   const int* __restrict__ rp,
                                                   const ushort_t* __restrict__ h3,
                                                   const float* __restrict__ dinv,
                                                   const float* __restrict__ bias,
                                                   float* __restrict__ out, int N) {
    __shared__ int srp[BNODES + 1];
    __shared__ uint_t cols[BCAP];
    int b = blockIdx.x, tid = threadIdx.x;
    if (tid <= BNODES) srp[tid] = rp[b * (BNODES + 1) + tid];
    __syncthreads();
    int cnt = srp[BNODES];
    for (int e = tid; e < cnt; e += 256) cols[e] = colsort[(size_t)b * BCAP + e];
    __syncthreads();
    int fo = tid & 7;                  // feature octant (8 feats, 16B)
    int g  = tid >> 3;                 // node slot 0..31
    bool act = fo < 5;
    float bv[8];
#pragma unroll
    for (int j = 0; j < 8; j++) bv[j] = act ? bias[fo * 8 + j] : 0.f;
    for (int nl = g; nl < BNODES; nl += 32) {
        int n = b * BNODES + nl;
        if (n >= N) break;
        int e = srp[nl], e1 = srp[nl + 1];
        float a[8] = {0.f, 0.f, 0.f, 0.f, 0.f, 0.f, 0.f, 0.f};
        if (act) {
            uint4 sv = *(const uint4*)&h3[(size_t)n * 64 + fo * 8];
            a[0] = lo2f(sv.x); a[1] = hi2f(sv.x); a[2] = lo2f(sv.y); a[3] = hi2f(sv.y);
            a[4] = lo2f(sv.z); a[5] = hi2f(sv.z); a[6] = lo2f(sv.w); a[7] = hi2f(sv.w);
        }
        for (; e + 4 <= e1; e += 4) {
            if (act) {
                uint4 v[4];
#pragma unroll
                for (int i = 0; i < 4; i++) v[i] = *(const uint4*)&h3[(size_t)cols[e + i] * 64 + fo * 8];
#pragma unroll
                for (int i = 0; i < 4; i++) {
                    a[0] = dot2bf(v[i].x, LOMASK, a[0]); a[1] = dot2bf(v[i].x, HIMASK, a[1]);
                    a[2] = dot2bf(v[i].y, LOMASK, a[2]); a[3] = dot2bf(v[i].y, HIMASK, a[3]);
                    a[4] = dot2bf(v[i].z, LOMASK, a[4]); a[5] = dot2bf(v[i].z, HIMASK, a[5]);
                    a[6] = dot2bf(v[i].w, LOMASK, a[6]); a[7] = dot2bf(v[i].w, HIMASK, a[7]);
                }
            }
        }
        for (; e < e1; e++) {
            if (act) {
                uint4 v = *(const uint4*)&h3[(size_t)cols[e] * 64 + fo * 8];
                a[0] = dot2bf(v.x, LOMASK, a[0]); a[1] = dot2bf(v.x, HIMASK, a[1]);
                a[2] = dot2bf(v.y, LOMASK, a[2]); a[3] = dot2bf(v.y, HIMASK, a[3]);
                a[4] = dot2bf(v.z, LOMASK, a[4]); a[5] = dot2bf(v.z, HIMASK, a[5]);
                a[6] = dot2bf(v.w, LOMASK, a[6]); a[7] = dot2bf(v.w, HIMASK, a[7]);
            }
        }
        float dn = dinv[n];
        float z[8];
        float m = -INFINITY;
#pragma unroll
        for (int j = 0; j < 8; j++) {
            z[j] = act ? fmaf(dn, a[j], bv[j]) : -INFINITY;
            m = fmaxf(m, z[j]);
        }
#pragma unroll
        for (int off = 4; off; off >>= 1) m = fmaxf(m, __shfl_xor(m, off, 8));
        float p = 0.f;
        if (act) {
#pragma unroll
            for (int j = 0; j < 8; j++) p += expf(z[j] - m);
        }
#pragma unroll
        for (int off = 4; off; off >>= 1) p += __shfl_xor(p, off, 8);
        float lse = m + logf(p);
        if (act) {
            float4 o0 = make_float4(z[0] - lse, z[1] - lse, z[2] - lse, z[3] - lse);
            float4 o1 = make_float4(z[4] - lse, z[5] - lse, z[6] - lse, z[7] - lse);
            *(float4*)&out[(size_t)n * NCLASS + fo * 8]     = o0;
            *(float4*)&out[(size_t)n * NCLASS + fo * 8 + 4] = o1;
        }
    }
}

// ---------------- launch ----------------

extern "C" void kernel_launch(void* const* d_in, const int* in_sizes, int n_in,
                              void* d_out, int out_size, void* d_ws, size_t ws_size,
                              hipStream_t stream) {
    const float* x  = (const float*)d_in[0];
    const int*   ei = (const int*)d_in[1];
    const float* W1 = (const float*)d_in[2];
    const float* b1 = (const float*)d_in[3];
    const float* W2 = (const float*)d_in[4];
    const float* b2 = (const float*)d_in[5];
    const float* W3 = (const float*)d_in[6];
    const float* b3 = (const float*)d_in[7];
    float* out = (float*)d_out;
    const int N = in_sizes[0] / NFEAT;
    const int E = in_sizes[1] / 2;
    const int* src = ei;
    const int* dst = ei + E;
    const int NBK = (N + BNODES - 1) / BNODES;
    const int NBLK_E = (E + EPB - 1) / EPB;

    char* ws = (char*)d_ws;
    size_t off = 0;
    auto alloc = [&](size_t bytes) -> void* {
        void* p = ws + off;
        off += (bytes + 255) & ~(size_t)255;
        return p;
    };
    int*      bcnt    = (int*)alloc((size_t)NBK * 4);
    int*      ecnt    = (int*)alloc((size_t)NBK * NBLK_E * 4);
    uint_t*   bstore  = (uint_t*)alloc((size_t)NBK * BCAP * 4);
    uint_t*   colsort = (uint_t*)alloc((size_t)NBK * BCAP * 4);
    int*      rp      = (int*)alloc((size_t)NBK * (BNODES + 1) * 4);
    float*    dinv    = (float*)alloc((size_t)N * 4);
    ushort_t* hsl     = (ushort_t*)alloc((size_t)N * NHID * 2);
    ushort_t* abuf    = (ushort_t*)alloc((size_t)N * NHID * 2);
    ushort_t* h3      = (ushort_t*)alloc((size_t)N * 64 * 2);     // padded [N][64]
    ushort_t* Whi1    = (ushort_t*)alloc((size_t)NHID * NFEAT * 2);
    ushort_t* Whi2    = (ushort_t*)alloc((size_t)NHID * NHID * 2);
    ushort_t* Whi3    = (ushort_t*)alloc((size_t)64 * NHID * 2);  // padded [64][128]
    (void)ws_size; (void)n_in; (void)out_size;

    // fused weight prep
    int wtelems = NHID * NFEAT + NHID * NHID + 64 * NHID;
    k_wtall<<<(wtelems + 255) / 256, 256, 0, stream>>>(W1, W2, W3, Whi1, Whi2, Whi3);

    // edge partition (no global atomics) + per-bucket sort + dinv
    k_ehist<<<NBLK_E, 256, 0, stream>>>(dst, ecnt, E, NBK, NBLK_E);
    k_escan<<<NBK, 128, 0, stream>>>(ecnt, bcnt, NBLK_E);
    k_escatter<<<NBLK_E, 256, 0, stream>>>(src, dst, ecnt, bstore, E, NBK, NBLK_E);
    k_bsort<<<NBK, 256, 0, stream>>>(bstore, bcnt, colsort, rp, dinv, N);

    int ngemm = (N + 63) / 64;
    // layer 1
    k_gemm_mfma<NFEAT, true, 128, 0, 0><<<ngemm, 256, 0, stream>>>(x, Whi1, dinv, hsl, N);
    k_agg_slice<<<NBK * 4, 256, 0, stream>>>(colsort, rp, hsl, dinv, b1, abuf, N);
    // layer 2
    k_gemm_mfma<NHID, false, 128, 0, 0><<<ngemm, 256, 0, stream>>>(abuf, Whi2, dinv, hsl, N);
    k_agg_slice<<<NBK * 4, 256, 0, stream>>>(colsort, rp, hsl, dinv, b2, abuf, N);
    // layer 3 + log_softmax
    k_gemm_mfma<NHID, false, 64, 64, 1><<<ngemm, 256, 0, stream>>>(abuf, Whi3, dinv, h3, N);
    k_agg40_lsm<<<NBK, 256, 0, stream>>>(colsort, rp, h3, dinv, b3, out, N);
}

// Round 15
// 244.970 us; speedup vs baseline: 1.3524x; 1.1956x over previous
//
#include <hip/hip_runtime.h>
#include <math.h>

#define NFEAT 256
#define NHID 128
#define NCLASS 40
#define BNODES 128
#define BSHIFT 7
#define BCAP 2688
#define MAXBK 1024
#define EPB 16384

typedef unsigned short ushort_t;
typedef unsigned int uint_t;
typedef unsigned char uchar_t;
typedef __attribute__((ext_vector_type(8))) short bf16x8;
typedef __attribute__((ext_vector_type(4))) float f32x4;
typedef __attribute__((ext_vector_type(2))) float f32x2;

static __device__ inline float bf2f(ushort_t u) {
    union { uint_t u; float f; } v; v.u = (uint_t)u << 16; return v.f;
}
static __device__ inline float lo2f(uint_t u) {
    union { uint_t u; float f; } v; v.u = u << 16; return v.f;
}
static __device__ inline float hi2f(uint_t u) {
    union { uint_t u; float f; } v; v.u = u & 0xFFFF0000u; return v.f;
}
static __device__ inline ushort_t f2bf(float f) {
    uint_t u = __float_as_uint(f);
    u += 0x7FFF + ((u >> 16) & 1);           // round-to-nearest-even
    return (ushort_t)(u >> 16);
}
// fused bf16-extract + fp32 accumulate
static __device__ inline float dot2bf(uint_t pk, uint_t mask, float c) {
    float r;
    asm("v_dot2_f32_bf16 %0, %1, %2, %3" : "=v"(r) : "v"(pk), "v"(mask), "v"(c));
    return r;
}
#define LOMASK 0x00003F80u
#define HIMASK 0x3F800000u

// async global->LDS 16B (dest = wave-uniform base + lane*16)
static __device__ __forceinline__ void gload16(const void* g, void* l) {
    __builtin_amdgcn_global_load_lds(
        (const __attribute__((address_space(1))) uint_t*)g,
        (__attribute__((address_space(3))) uint_t*)l, 16, 0, 0);
}

// fp8 e4m3 pack/unpack (gfx950 native)
static __device__ inline ushort_t pk2fp8(float a, float b) {
    return (ushort_t)__builtin_amdgcn_cvt_pk_fp8_f32(a, b, 0, false);
}
static __device__ inline f32x2 unpk_lo(uint_t w) {
    return __builtin_amdgcn_cvt_pk_f32_fp8(w, false);
}
static __device__ inline f32x2 unpk_hi(uint_t w) {
    return __builtin_amdgcn_cvt_pk_f32_fp8(w, true);
}

// ---------------- edge partition by dst-bucket: hist / scan / scatter --------

__global__ __launch_bounds__(256) void k_ehist(const int* __restrict__ dst,
                                               int* __restrict__ cnt,
                                               int E, int nbk, int nblk) {
    __shared__ int hist[MAXBK];
    int tid = threadIdx.x, be = blockIdx.x;
    for (int i = tid; i < nbk; i += 256) hist[i] = 0;
    __syncthreads();
    int e0 = be * EPB, e1 = min(e0 + EPB, E);
    for (int e = e0 + tid; e < e1; e += 256)
        atomicAdd(&hist[dst[e] >> BSHIFT], 1);          // LDS int atomic: native
    __syncthreads();
    for (int i = tid; i < nbk; i += 256)
        cnt[(size_t)i * nblk + be] = hist[i];
}

__global__ __launch_bounds__(128) void k_escan(int* __restrict__ cnt,
                                               int* __restrict__ bcnt, int nblk) {
    __shared__ int buf[128];
    int b = blockIdx.x, tid = threadIdx.x;
    int v = (tid < nblk) ? cnt[(size_t)b * nblk + tid] : 0;
    buf[tid] = v;
    __syncthreads();
    for (int off = 1; off < 128; off <<= 1) {
        int t = (tid >= off) ? buf[tid - off] : 0;
        __syncthreads();
        buf[tid] += t;
        __syncthreads();
    }
    if (tid < nblk) cnt[(size_t)b * nblk + tid] = buf[tid] - v;   // exclusive
    if (tid == 127) bcnt[b] = buf[127];                           // total
}

__global__ __launch_bounds__(256) void k_escatter(const int* __restrict__ src,
                                                  const int* __restrict__ dst,
                                                  const int* __restrict__ cnt,
                                                  uint_t* __restrict__ bstore,
                                                  int E, int nbk, int nblk) {
    __shared__ int cur[MAXBK];
    int tid = threadIdx.x, be = blockIdx.x;
    for (int i = tid; i < nbk; i += 256)
        cur[i] = cnt[(size_t)i * nblk + be];
    __syncthreads();
    int e0 = be * EPB, e1 = min(e0 + EPB, E);
    for (int e = e0 + tid; e < e1; e += 256) {
        int d = dst[e];
        int b = d >> BSHIFT;
        int p = atomicAdd(&cur[b], 1);                  // LDS int atomic: native
        if (p < BCAP)
            bstore[(size_t)b * BCAP + p] = ((uint_t)(d & (BNODES - 1)) << 20) | (uint_t)src[e];
    }
}

// ---------------- per-bucket counting sort (LDS), + rp + dinv ----------------

__global__ __launch_bounds__(256) void k_bsort(const uint_t* __restrict__ bstore,
                                               const int* __restrict__ bcnt,
                                               uint_t* __restrict__ colsort,
                                               int* __restrict__ rp,
                                               float* __restrict__ dinv, int N) {
    __shared__ uint_t rec[BCAP];
    __shared__ uint_t srt[BCAP];
    __shared__ int hist[BNODES];
    __shared__ int scan[BNODES];
    __shared__ int cur[BNODES];
    int b = blockIdx.x, tid = threadIdx.x;
    if (tid < BNODES) hist[tid] = 0;
    __syncthreads();
    int cnt = min(bcnt[b], BCAP);
    const uint_t* gp = &bstore[(size_t)b * BCAP];
    for (int e = tid; e < cnt; e += 256) {
        uint_t r = gp[e];
        rec[e] = r;
        atomicAdd(&hist[r >> 20], 1);          // int LDS atomic: native
    }
    __syncthreads();
    if (tid < BNODES) scan[tid] = hist[tid];
    __syncthreads();
    for (int off = 1; off < BNODES; off <<= 1) {
        int v = 0;
        if (tid < BNODES && tid >= off) v = scan[tid - off];
        __syncthreads();
        if (tid < BNODES) scan[tid] += v;
        __syncthreads();
    }
    if (tid < BNODES) cur[tid] = scan[tid] - hist[tid];   // exclusive
    __syncthreads();
    for (int e = tid; e < cnt; e += 256) {
        uint_t r = rec[e];
        int p = atomicAdd(&cur[r >> 20], 1);   // int LDS atomic: native
        srt[p] = r & 0xFFFFF;
    }
    __syncthreads();
    uint_t* cs = &colsort[(size_t)b * BCAP];
    for (int e = tid; e < cnt; e += 256) cs[e] = srt[e];
    if (tid < BNODES) {
        rp[b * (BNODES + 1) + tid] = scan[tid] - hist[tid];
        int n = b * BNODES + tid;
        if (n < N) dinv[n] = rsqrtf((float)hist[tid] + 1.0f);
    }
    if (tid == 0) rp[b * (BNODES + 1) + BNODES] = cnt;
}

// ---------------- fused weight transpose -> bf16 -----------------------------
// T2,T3 rows permuted on k: within each 32-slice, phys kp -> logical
// k = (kp&1)*16 + (kp>>1)  (matches fp8 byte-pair pack of the previous layer)

__global__ __launch_bounds__(256) void k_wtall(const float* __restrict__ W1,
                                               const float* __restrict__ W2,
                                               const float* __restrict__ W3,
                                               ushort_t* __restrict__ T1,
                                               ushort_t* __restrict__ T2,
                                               ushort_t* __restrict__ T3) {
    int idx = blockIdx.x * 256 + threadIdx.x;
    if (idx < NHID * NFEAT) {                                // T1[128][256] (no perm)
        int nrow = idx >> 8, k = idx & 255;
        T1[idx] = f2bf(W1[(size_t)k * NHID + nrow]);
    } else if ((idx -= NHID * NFEAT) < NHID * NHID) {        // T2[128][128] k-perm
        int nrow = idx >> 7, kp = idx & 127;
        int s = kp >> 5, pl = kp & 31;
        int k = s * 32 + ((pl & 1) << 4) + (pl >> 1);
        T2[idx] = f2bf(W2[(size_t)k * NHID + nrow]);
    } else if ((idx -= NHID * NHID) < 64 * NHID) {           // T3[64][128] k-perm, pad
        int nrow = idx >> 7, kp = idx & 127;
        int s = kp >> 5, pl = kp & 31;
        int k = s * 32 + ((pl & 1) << 4) + (pl >> 1);
        T3[idx] = f2bf(nrow < NCLASS ? W3[(size_t)k * NCLASS + nrow] : 0.f);
    }
}

// ---------------- MFMA GEMM (bf16 weights, BM=64, BK=64, async LDS stage) ----
// C = (A @ W) * dinv[row]   (pre-scaled h')
// MODE 0: out fp8 e4m3, slice-major [4][N][32] (32B rows), byte-pair packed
// MODE 1: out bf16 row-major [N][OST]
// A_FP32: A row-major fp32 (convert path); else A bf16 slice-major [K/32][N][32]

template<int K, bool A_FP32, int BN, int OST, int MODE>
__global__ __launch_bounds__(256) void k_gemm_mfma(const void* __restrict__ Ap,
                                                   const ushort_t* __restrict__ Whi,
                                                   const float* __restrict__ dinv,
                                                   void* __restrict__ Cv, int n) {
    const int BM = 64, BK = 64;
    __shared__ ushort_t As[BM * BK];
    __shared__ ushort_t Bh[BN * BK];
    const int tid = threadIdx.x;
    const int w = tid >> 6, l = tid & 63;
    const int row0 = blockIdx.x * BM;
    const int NJ = BN / 16;
    f32x4 acc[NJ] = {};

    for (int k0 = 0; k0 < K; k0 += BK) {
        // ---- stage A tile (64 x 64) ----
        if (A_FP32) {
            int r = tid >> 2;
            if (row0 + r < n) {
                const float* A = (const float*)Ap;
                const float* ap = &A[(size_t)(row0 + r) * K + k0];
#pragma unroll
                for (int h = 0; h < 2; h++) {
                    int q = (tid & 3) * 2 + h;
                    float4 v0 = *(const float4*)&ap[q * 8];
                    float4 v1 = *(const float4*)&ap[q * 8 + 4];
                    ushort4 o0, o1;
                    o0.x = f2bf(v0.x); o0.y = f2bf(v0.y); o0.z = f2bf(v0.z); o0.w = f2bf(v0.w);
                    o1.x = f2bf(v1.x); o1.y = f2bf(v1.y); o1.z = f2bf(v1.z); o1.w = f2bf(v1.w);
                    int pc = q ^ (r & 7);
                    *(ushort4*)&As[r * 64 + pc * 8]     = o0;
                    *(ushort4*)&As[r * 64 + pc * 8 + 4] = o1;
                }
            }
        } else {
            const ushort_t* A = (const ushort_t*)Ap;
#pragma unroll
            for (int m = 0; m < 2; m++) {
                int unit = m * 256 + tid;
                int r = unit >> 3, pc = unit & 7;
                int lc = pc ^ (r & 7);
                int kk = k0 + lc * 8;
                size_t rowg = (size_t)min(row0 + r, n - 1);   // clamp: junk rows unused
                const ushort_t* src = &A[(size_t)(kk >> 5) * n * 32 + rowg * 32 + (kk & 31)];
                gload16(src, &As[(size_t)unit * 8]);
            }
        }
        // ---- stage B tile (BN x 64) ----
#pragma unroll
        for (int m = 0; m < BN / 32; m++) {
            int unit = m * 256 + tid;
            int r = unit >> 3, pc = unit & 7;
            int lc = pc ^ (r & 7);
            gload16(&Whi[(size_t)r * K + k0 + lc * 8], &Bh[(size_t)unit * 8]);
        }
        __syncthreads();   // drains vmcnt + lgkmcnt

        const int lo4 = l & 15;
        const int swz = l & 7;
#pragma unroll
        for (int kh = 0; kh < BK; kh += 32) {
            int q = (kh >> 3) + (l >> 4);
            int ra = w * 16 + lo4;
            bf16x8 a = *(const bf16x8*)&As[ra * 64 + (q ^ swz) * 8];
#pragma unroll
            for (int j = 0; j < NJ; j++) {
                int rb = j * 16 + lo4;
                bf16x8 bh = *(const bf16x8*)&Bh[rb * 64 + (q ^ swz) * 8];
                acc[j] = __builtin_amdgcn_mfma_f32_16x16x32_bf16(a, bh, acc[j], 0, 0, 0);
            }
        }
        __syncthreads();
    }

    float dnv[4];
#pragma unroll
    for (int r = 0; r < 4; r++) {
        int row = row0 + w * 16 + (l >> 4) * 4 + r;
        dnv[r] = (row < n) ? dinv[row] : 0.f;
    }
    const int cb = l & 15;
    if (MODE == 0) {
        // fp8 pack: lane packs (col cb, col cb+16) of slice s -> bytes (2cb, 2cb+1)
        uchar_t* C8 = (uchar_t*)Cv;
#pragma unroll
        for (int s = 0; s < NJ / 2; s++) {
#pragma unroll
            for (int r = 0; r < 4; r++) {
                int row = row0 + w * 16 + (l >> 4) * 4 + r;
                if (row < n) {
                    ushort_t pk = pk2fp8(dnv[r] * acc[2 * s][r], dnv[r] * acc[2 * s + 1][r]);
                    *(ushort_t*)&C8[(size_t)s * n * 32 + (size_t)row * 32 + cb * 2] = pk;
                }
            }
        }
    } else {
        ushort_t* C = (ushort_t*)Cv;
#pragma unroll
        for (int j = 0; j < NJ; j++) {
#pragma unroll
            for (int r = 0; r < 4; r++) {
                int row = row0 + w * 16 + (l >> 4) * 4 + r;
                if (row < n)
                    C[(size_t)row * OST + j * 16 + cb] = f2bf(dnv[r] * acc[j][r]);
            }
        }
    }
}

// ---------------- sliced aggregation (layers 1,2) — fp8 32B rows, L2-fit ----
// block=(bucket,slice); slice=blk&3; h8 [4][N][32] fp8 (phys byte order)
// 2 lanes/node x uint4 (16 fp8 feats); out bf16 [4][N][32] in SAME phys order
// (next GEMM's W rows are permuted to match)

__global__ __launch_bounds__(256) void k_agg_slice(const uint_t* __restrict__ colsort,
                                                   const int* __restrict__ rp,
                                                   const uchar_t* __restrict__ h8,
                                                   const float* __restrict__ dinv,
                                                   const float* __restrict__ bias,
                                                   ushort_t* __restrict__ out, int N) {
    __shared__ int srp[BNODES + 1];
    __shared__ uint_t cols[BCAP];
    int blk = blockIdx.x;
    int slice = blk & 3, b = blk >> 2;
    int tid = threadIdx.x;
    if (tid <= BNODES) srp[tid] = rp[b * (BNODES + 1) + tid];
    __syncthreads();
    int cnt = srp[BNODES];
    for (int e = tid; e < cnt; e += 256) cols[e] = colsort[(size_t)b * BCAP + e];
    __syncthreads();
    int fh = tid & 1;                  // 16B half of the 32B row (16 fp8 feats)
    int nl = tid >> 1;                 // node slot 0..127
    int n = b * BNODES + nl;
    if (n >= N) return;
    const uchar_t* hs = &h8[(size_t)slice * N * 32 + fh * 16];
    // bias for phys slot p = fh*16+i : logical c = (p&1)*16 + (p>>1)
    float bv[16];
#pragma unroll
    for (int i = 0; i < 16; i++) {
        int p = fh * 16 + i;
        bv[i] = bias[slice * 32 + ((p & 1) << 4) + (p >> 1)];
    }
    int e = srp[nl], e1 = srp[nl + 1];
    f32x2 a2[8];
    {
        uint4 sv = *(const uint4*)&hs[(size_t)n * 32];
        a2[0] = unpk_lo(sv.x); a2[1] = unpk_hi(sv.x);
        a2[2] = unpk_lo(sv.y); a2[3] = unpk_hi(sv.y);
        a2[4] = unpk_lo(sv.z); a2[5] = unpk_hi(sv.z);
        a2[6] = unpk_lo(sv.w); a2[7] = unpk_hi(sv.w);
    }
    for (; e + 4 <= e1; e += 4) {
        uint4 v[4];
#pragma unroll
        for (int i = 0; i < 4; i++) v[i] = *(const uint4*)&hs[(size_t)cols[e + i] * 32];
#pragma unroll
        for (int i = 0; i < 4; i++) {
            a2[0] += unpk_lo(v[i].x); a2[1] += unpk_hi(v[i].x);
            a2[2] += unpk_lo(v[i].y); a2[3] += unpk_hi(v[i].y);
            a2[4] += unpk_lo(v[i].z); a2[5] += unpk_hi(v[i].z);
            a2[6] += unpk_lo(v[i].w); a2[7] += unpk_hi(v[i].w);
        }
    }
    for (; e < e1; e++) {
        uint4 v = *(const uint4*)&hs[(size_t)cols[e] * 32];
        a2[0] += unpk_lo(v.x); a2[1] += unpk_hi(v.x);
        a2[2] += unpk_lo(v.y); a2[3] += unpk_hi(v.y);
        a2[4] += unpk_lo(v.z); a2[5] += unpk_hi(v.z);
        a2[6] += unpk_lo(v.w); a2[7] += unpk_hi(v.w);
    }
    float dn = dinv[n];
    uint_t o[8];
#pragma unroll
    for (int k = 0; k < 8; k++) {
        float r0 = fmaxf(fmaf(dn, a2[k].x, bv[2 * k]),     0.f);
        float r1 = fmaxf(fmaf(dn, a2[k].y, bv[2 * k + 1]), 0.f);
        o[k] = ((uint_t)f2bf(r1) << 16) | f2bf(r0);
    }
    ushort_t* op = &out[((size_t)slice * N + n) * 32 + fh * 16];
    *(uint4*)&op[0] = make_uint4(o[0], o[1], o[2], o[3]);
    *(uint4*)&op[8] = make_uint4(o[4], o[5], o[6], o[7]);
}

// ---------------- layer-3 aggregation + log_softmax — padded 128B rows ------
// h3 row-major [N][64] bf16 pre-scaled (cols >= 40 junk, never read)

__global__ __launch_bounds__(256) void k_agg40_lsm(const uint_t* __restrict__ colsort,
                                                   const int* __restrict__ rp,
                                                   const ushort_t* __restrict__ h3,
                                                   const float* __restrict__ dinv,
                                                   const float* __restrict__ bias,
                                                   float* __restrict__ out, int N) {
    __shared__ int srp[BNODES + 1];
    __shared__ uint_t cols[BCAP];
    int b = blockIdx.x, tid = threadIdx.x;
    if (tid <= BNODES) srp[tid] = rp[b * (BNODES + 1) + tid];
    __syncthreads();
    int cnt = srp[BNODES];
    for (int e = tid; e < cnt; e += 256) cols[e] = colsort[(size_t)b * BCAP + e];
    __syncthreads();
    int fo = tid & 7;                  // feature octant (8 feats, 16B)
    int g  = tid >> 3;                 // node slot 0..31
    bool act = fo < 5;
    float bv[8];
#pragma unroll
    for (int j = 0; j < 8; j++) bv[j] = act ? bias[fo * 8 + j] : 0.f;
    for (int nl = g; nl < BNODES; nl += 32) {
        int n = b * BNODES + nl;
        if (n >= N) break;
        int e = srp[nl], e1 = srp[nl + 1];
        float a[8] = {0.f, 0.f, 0.f, 0.f, 0.f, 0.f, 0.f, 0.f};
        if (act) {
            uint4 sv = *(const uint4*)&h3[(size_t)n * 64 + fo * 8];
            a[0] = lo2f(sv.x); a[1] = hi2f(sv.x); a[2] = lo2f(sv.y); a[3] = hi2f(sv.y);
            a[4] = lo2f(sv.z); a[5] = hi2f(sv.z); a[6] = lo2f(sv.w); a[7] = hi2f(sv.w);
        }
        for (; e + 4 <= e1; e += 4) {
            if (act) {
                uint4 v[4];
#pragma unroll
                for (int i = 0; i < 4; i++) v[i] = *(const uint4*)&h3[(size_t)cols[e + i] * 64 + fo * 8];
#pragma unroll
                for (int i = 0; i < 4; i++) {
                    a[0] = dot2bf(v[i].x, LOMASK, a[0]); a[1] = dot2bf(v[i].x, HIMASK, a[1]);
                    a[2] = dot2bf(v[i].y, LOMASK, a[2]); a[3] = dot2bf(v[i].y, HIMASK, a[3]);
                    a[4] = dot2bf(v[i].z, LOMASK, a[4]); a[5] = dot2bf(v[i].z, HIMASK, a[5]);
                    a[6] = dot2bf(v[i].w, LOMASK, a[6]); a[7] = dot2bf(v[i].w, HIMASK, a[7]);
                }
            }
        }
        for (; e < e1; e++) {
            if (act) {
                uint4 v = *(const uint4*)&h3[(size_t)cols[e] * 64 + fo * 8];
                a[0] = dot2bf(v.x, LOMASK, a[0]); a[1] = dot2bf(v.x, HIMASK, a[1]);
                a[2] = dot2bf(v.y, LOMASK, a[2]); a[3] = dot2bf(v.y, HIMASK, a[3]);
                a[4] = dot2bf(v.z, LOMASK, a[4]); a[5] = dot2bf(v.z, HIMASK, a[5]);
                a[6] = dot2bf(v.w, LOMASK, a[6]); a[7] = dot2bf(v.w, HIMASK, a[7]);
            }
        }
        float dn = dinv[n];
        float z[8];
        float m = -INFINITY;
#pragma unroll
        for (int j = 0; j < 8; j++) {
            z[j] = act ? fmaf(dn, a[j], bv[j]) : -INFINITY;
            m = fmaxf(m, z[j]);
        }
#pragma unroll
        for (int off = 4; off; off >>= 1) m = fmaxf(m, __shfl_xor(m, off, 8));
        float p = 0.f;
        if (act) {
#pragma unroll
            for (int j = 0; j < 8; j++) p += expf(z[j] - m);
        }
#pragma unroll
        for (int off = 4; off; off >>= 1) p += __shfl_xor(p, off, 8);
        float lse = m + logf(p);
        if (act) {
            float4 o0 = make_float4(z[0] - lse, z[1] - lse, z[2] - lse, z[3] - lse);
            float4 o1 = make_float4(z[4] - lse, z[5] - lse, z[6] - lse, z[7] - lse);
            *(float4*)&out[(size_t)n * NCLASS + fo * 8]     = o0;
            *(float4*)&out[(size_t)n * NCLASS + fo * 8 + 4] = o1;
        }
    }
}

// ---------------- launch ----------------

extern "C" void kernel_launch(void* const* d_in, const int* in_sizes, int n_in,
                              void* d_out, int out_size, void* d_ws, size_t ws_size,
                              hipStream_t stream) {
    const float* x  = (const float*)d_in[0];
    const int*   ei = (const int*)d_in[1];
    const float* W1 = (const float*)d_in[2];
    const float* b1 = (const float*)d_in[3];
    const float* W2 = (const float*)d_in[4];
    const float* b2 = (const float*)d_in[5];
    const float* W3 = (const float*)d_in[6];
    const float* b3 = (const float*)d_in[7];
    float* out = (float*)d_out;
    const int N = in_sizes[0] / NFEAT;
    const int E = in_sizes[1] / 2;
    const int* src = ei;
    const int* dst = ei + E;
    const int NBK = (N + BNODES - 1) / BNODES;
    const int NBLK_E = (E + EPB - 1) / EPB;

    char* ws = (char*)d_ws;
    size_t off = 0;
    auto alloc = [&](size_t bytes) -> void* {
        void* p = ws + off;
        off += (bytes + 255) & ~(size_t)255;
        return p;
    };
    int*      bcnt    = (int*)alloc((size_t)NBK * 4);
    int*      ecnt    = (int*)alloc((size_t)NBK * NBLK_E * 4);
    uint_t*   bstore  = (uint_t*)alloc((size_t)NBK * BCAP * 4);
    uint_t*   colsort = (uint_t*)alloc((size_t)NBK * BCAP * 4);
    int*      rp      = (int*)alloc((size_t)NBK * (BNODES + 1) * 4);
    float*    dinv    = (float*)alloc((size_t)N * 4);
    uchar_t*  h8      = (uchar_t*)alloc((size_t)N * NHID);       // fp8 GEMM out [4][N][32]
    ushort_t* abuf    = (ushort_t*)alloc((size_t)N * NHID * 2);  // bf16 agg out (phys order)
    ushort_t* h3      = (ushort_t*)alloc((size_t)N * 64 * 2);    // padded [N][64] bf16
    ushort_t* Whi1    = (ushort_t*)alloc((size_t)NHID * NFEAT * 2);
    ushort_t* Whi2    = (ushort_t*)alloc((size_t)NHID * NHID * 2);
    ushort_t* Whi3    = (ushort_t*)alloc((size_t)64 * NHID * 2);
    (void)ws_size; (void)n_in; (void)out_size;

    // fused weight prep (T2/T3 k-permuted to match fp8 byte-pair order)
    int wtelems = NHID * NFEAT + NHID * NHID + 64 * NHID;
    k_wtall<<<(wtelems + 255) / 256, 256, 0, stream>>>(W1, W2, W3, Whi1, Whi2, Whi3);

    // edge partition (no global atomics) + per-bucket sort + dinv
    k_ehist<<<NBLK_E, 256, 0, stream>>>(dst, ecnt, E, NBK, NBLK_E);
    k_escan<<<NBK, 128, 0, stream>>>(ecnt, bcnt, NBLK_E);
    k_escatter<<<NBLK_E, 256, 0, stream>>>(src, dst, ecnt, bstore, E, NBK, NBLK_E);
    k_bsort<<<NBK, 256, 0, stream>>>(bstore, bcnt, colsort, rp, dinv, N);

    int ngemm = (N + 63) / 64;
    // layer 1
    k_gemm_mfma<NFEAT, true, 128, 0, 0><<<ngemm, 256, 0, stream>>>(x, Whi1, dinv, h8, N);
    k_agg_slice<<<NBK * 4, 256, 0, stream>>>(colsort, rp, h8, dinv, b1, abuf, N);
    // layer 2
    k_gemm_mfma<NHID, false, 128, 0, 0><<<ngemm, 256, 0, stream>>>(abuf, Whi2, dinv, h8, N);
    k_agg_slice<<<NBK * 4, 256, 0, stream>>>(colsort, rp, h8, dinv, b2, abuf, N);
    // layer 3 + log_softmax
    k_gemm_mfma<NHID, false, 64, 64, 1><<<ngemm, 256, 0, stream>>>(abuf, Whi3, dinv, h3, N);
    k_agg40_lsm<<<NBK, 256, 0, stream>>>(colsort, rp, h3, dinv, b3, out, N);
}

// Round 16
// 243.796 us; speedup vs baseline: 1.3590x; 1.0048x over previous
//
#include <hip/hip_runtime.h>
#include <math.h>

#define NFEAT 256
#define NHID 128
#define NCLASS 40
#define BNODES 128
#define BSHIFT 7
#define BCAP 2688
#define MAXBK 1024
#define EPB 16384

typedef unsigned short ushort_t;
typedef unsigned int uint_t;
typedef unsigned char uchar_t;
typedef __attribute__((ext_vector_type(8))) short bf16x8;
typedef __attribute__((ext_vector_type(4))) float f32x4;
typedef __attribute__((ext_vector_type(2))) float f32x2;

static __device__ inline float bf2f(ushort_t u) {
    union { uint_t u; float f; } v; v.u = (uint_t)u << 16; return v.f;
}
static __device__ inline float lo2f(uint_t u) {
    union { uint_t u; float f; } v; v.u = u << 16; return v.f;
}
static __device__ inline float hi2f(uint_t u) {
    union { uint_t u; float f; } v; v.u = u & 0xFFFF0000u; return v.f;
}
static __device__ inline ushort_t f2bf(float f) {
    uint_t u = __float_as_uint(f);
    u += 0x7FFF + ((u >> 16) & 1);           // round-to-nearest-even
    return (ushort_t)(u >> 16);
}
// fused bf16-extract + fp32 accumulate
static __device__ inline float dot2bf(uint_t pk, uint_t mask, float c) {
    float r;
    asm("v_dot2_f32_bf16 %0, %1, %2, %3" : "=v"(r) : "v"(pk), "v"(mask), "v"(c));
    return r;
}
#define LOMASK 0x00003F80u
#define HIMASK 0x3F800000u

// async global->LDS 16B (dest = wave-uniform base + lane*16)
static __device__ __forceinline__ void gload16(const void* g, void* l) {
    __builtin_amdgcn_global_load_lds(
        (const __attribute__((address_space(1))) uint_t*)g,
        (__attribute__((address_space(3))) uint_t*)l, 16, 0, 0);
}

// fp8 e4m3 pack/unpack (gfx950 native)
static __device__ inline ushort_t pk2fp8(float a, float b) {
    return (ushort_t)__builtin_amdgcn_cvt_pk_fp8_f32(a, b, 0, false);
}
static __device__ inline f32x2 unpk_lo(uint_t w) {
    return __builtin_amdgcn_cvt_pk_f32_fp8(w, false);
}
static __device__ inline f32x2 unpk_hi(uint_t w) {
    return __builtin_amdgcn_cvt_pk_f32_fp8(w, true);
}

// ---------------- edge partition by dst-bucket: hist / scan / scatter --------

__global__ __launch_bounds__(256) void k_ehist(const int* __restrict__ dst,
                                               int* __restrict__ cnt,
                                               int E, int nbk, int nblk) {
    __shared__ int hist[MAXBK];
    int tid = threadIdx.x, be = blockIdx.x;
    for (int i = tid; i < nbk; i += 256) hist[i] = 0;
    __syncthreads();
    int e0 = be * EPB, e1 = min(e0 + EPB, E);
    for (int e = e0 + tid; e < e1; e += 256)
        atomicAdd(&hist[dst[e] >> BSHIFT], 1);          // LDS int atomic: native
    __syncthreads();
    for (int i = tid; i < nbk; i += 256)
        cnt[(size_t)i * nblk + be] = hist[i];
}

__global__ __launch_bounds__(128) void k_escan(int* __restrict__ cnt,
                                               int* __restrict__ bcnt, int nblk) {
    __shared__ int buf[128];
    int b = blockIdx.x, tid = threadIdx.x;
    int v = (tid < nblk) ? cnt[(size_t)b * nblk + tid] : 0;
    buf[tid] = v;
    __syncthreads();
    for (int off = 1; off < 128; off <<= 1) {
        int t = (tid >= off) ? buf[tid - off] : 0;
        __syncthreads();
        buf[tid] += t;
        __syncthreads();
    }
    if (tid < nblk) cnt[(size_t)b * nblk + tid] = buf[tid] - v;   // exclusive
    if (tid == 127) bcnt[b] = buf[127];                           // total
}

__global__ __launch_bounds__(256) void k_escatter(const int* __restrict__ src,
                                                  const int* __restrict__ dst,
                                                  const int* __restrict__ cnt,
                                                  uint_t* __restrict__ bstore,
                                                  int E, int nbk, int nblk) {
    __shared__ int cur[MAXBK];
    int tid = threadIdx.x, be = blockIdx.x;
    for (int i = tid; i < nbk; i += 256)
        cur[i] = cnt[(size_t)i * nblk + be];
    __syncthreads();
    int e0 = be * EPB, e1 = min(e0 + EPB, E);
    for (int e = e0 + tid; e < e1; e += 256) {
        int d = dst[e];
        int b = d >> BSHIFT;
        int p = atomicAdd(&cur[b], 1);                  // LDS int atomic: native
        if (p < BCAP)
            bstore[(size_t)b * BCAP + p] = ((uint_t)(d & (BNODES - 1)) << 20) | (uint_t)src[e];
    }
}

// ---------------- per-bucket counting sort (LDS), + rp + dinv ----------------

__global__ __launch_bounds__(256) void k_bsort(const uint_t* __restrict__ bstore,
                                               const int* __restrict__ bcnt,
                                               uint_t* __restrict__ colsort,
                                               int* __restrict__ rp,
                                               float* __restrict__ dinv, int N) {
    __shared__ uint_t rec[BCAP];
    __shared__ uint_t srt[BCAP];
    __shared__ int hist[BNODES];
    __shared__ int scan[BNODES];
    __shared__ int cur[BNODES];
    int b = blockIdx.x, tid = threadIdx.x;
    if (tid < BNODES) hist[tid] = 0;
    __syncthreads();
    int cnt = min(bcnt[b], BCAP);
    const uint_t* gp = &bstore[(size_t)b * BCAP];
    for (int e = tid; e < cnt; e += 256) {
        uint_t r = gp[e];
        rec[e] = r;
        atomicAdd(&hist[r >> 20], 1);          // int LDS atomic: native
    }
    __syncthreads();
    if (tid < BNODES) scan[tid] = hist[tid];
    __syncthreads();
    for (int off = 1; off < BNODES; off <<= 1) {
        int v = 0;
        if (tid < BNODES && tid >= off) v = scan[tid - off];
        __syncthreads();
        if (tid < BNODES) scan[tid] += v;
        __syncthreads();
    }
    if (tid < BNODES) cur[tid] = scan[tid] - hist[tid];   // exclusive
    __syncthreads();
    for (int e = tid; e < cnt; e += 256) {
        uint_t r = rec[e];
        int p = atomicAdd(&cur[r >> 20], 1);   // int LDS atomic: native
        srt[p] = r & 0xFFFFF;
    }
    __syncthreads();
    uint_t* cs = &colsort[(size_t)b * BCAP];
    for (int e = tid; e < cnt; e += 256) cs[e] = srt[e];
    if (tid < BNODES) {
        rp[b * (BNODES + 1) + tid] = scan[tid] - hist[tid];
        int n = b * BNODES + tid;
        if (n < N) dinv[n] = rsqrtf((float)hist[tid] + 1.0f);
    }
    if (tid == 0) rp[b * (BNODES + 1) + BNODES] = cnt;
}

// ---------------- fused weight transpose -> bf16 -----------------------------
// T2,T3 rows permuted on k: within each 32-slice, phys kp -> logical
// k = (kp&1)*16 + (kp>>1)  (matches fp8 byte-pair pack of the previous layer)

__global__ __launch_bounds__(256) void k_wtall(const float* __restrict__ W1,
                                               const float* __restrict__ W2,
                                               const float* __restrict__ W3,
                                               ushort_t* __restrict__ T1,
                                               ushort_t* __restrict__ T2,
                                               ushort_t* __restrict__ T3) {
    int idx = blockIdx.x * 256 + threadIdx.x;
    if (idx < NHID * NFEAT) {                                // T1[128][256] (no perm)
        int nrow = idx >> 8, k = idx & 255;
        T1[idx] = f2bf(W1[(size_t)k * NHID + nrow]);
    } else if ((idx -= NHID * NFEAT) < NHID * NHID) {        // T2[128][128] k-perm
        int nrow = idx >> 7, kp = idx & 127;
        int s = kp >> 5, pl = kp & 31;
        int k = s * 32 + ((pl & 1) << 4) + (pl >> 1);
        T2[idx] = f2bf(W2[(size_t)k * NHID + nrow]);
    } else if ((idx -= NHID * NHID) < 64 * NHID) {           // T3[64][128] k-perm, pad
        int nrow = idx >> 7, kp = idx & 127;
        int s = kp >> 5, pl = kp & 31;
        int k = s * 32 + ((pl & 1) << 4) + (pl >> 1);
        T3[idx] = f2bf(nrow < NCLASS ? W3[(size_t)k * NCLASS + nrow] : 0.f);
    }
}

// ---------------- MFMA GEMM (bf16 weights, BM=128, 512 thr / 8 waves) -------
// C = (A @ W) * dinv[row]   (pre-scaled h')
// BK=64; LDS: A 16KB + B 16KB -> 4 blocks/CU x 8 waves = full occupancy
// MODE 0: out fp8 e4m3, slice-major [4][N][32] (32B rows), byte-pair packed
// MODE 1: out bf16 row-major [N][OST]
// A_FP32: A row-major fp32 (convert path); else A bf16 slice-major [K/32][N][32]

template<int K, bool A_FP32, int BN, int OST, int MODE>
__global__ __launch_bounds__(512) void k_gemm_mfma(const void* __restrict__ Ap,
                                                   const ushort_t* __restrict__ Whi,
                                                   const float* __restrict__ dinv,
                                                   void* __restrict__ Cv, int n) {
    const int BM = 128, BK = 64;
    __shared__ ushort_t As[BM * BK];
    __shared__ ushort_t Bh[BN * BK];
    const int tid = threadIdx.x;
    const int w = tid >> 6, l = tid & 63;
    const int row0 = blockIdx.x * BM;
    const int NJ = BN / 16;
    f32x4 acc[NJ] = {};

    for (int k0 = 0; k0 < K; k0 += BK) {
        // ---- stage A tile (128 x 64) ----
        if (A_FP32) {
            int r = tid >> 2;                       // 0..127
            if (row0 + r < n) {
                const float* A = (const float*)Ap;
                const float* ap = &A[(size_t)(row0 + r) * K + k0];
#pragma unroll
                for (int h = 0; h < 2; h++) {
                    int q = (tid & 3) * 2 + h;
                    float4 v0 = *(const float4*)&ap[q * 8];
                    float4 v1 = *(const float4*)&ap[q * 8 + 4];
                    ushort4 o0, o1;
                    o0.x = f2bf(v0.x); o0.y = f2bf(v0.y); o0.z = f2bf(v0.z); o0.w = f2bf(v0.w);
                    o1.x = f2bf(v1.x); o1.y = f2bf(v1.y); o1.z = f2bf(v1.z); o1.w = f2bf(v1.w);
                    int pc = q ^ (r & 7);
                    *(ushort4*)&As[r * 64 + pc * 8]     = o0;
                    *(ushort4*)&As[r * 64 + pc * 8 + 4] = o1;
                }
            }
        } else {
            const ushort_t* A = (const ushort_t*)Ap;
#pragma unroll
            for (int m = 0; m < 2; m++) {           // 1024 chunks, 2 rounds of 512
                int unit = m * 512 + tid;
                int r = unit >> 3, pc = unit & 7;
                int lc = pc ^ (r & 7);
                int kk = k0 + lc * 8;
                size_t rowg = (size_t)min(row0 + r, n - 1);   // clamp: junk rows unused
                const ushort_t* srcp = &A[(size_t)(kk >> 5) * n * 32 + rowg * 32 + (kk & 31)];
                gload16(srcp, &As[(size_t)unit * 8]);
            }
        }
        // ---- stage B tile (BN x 64): BN*8 chunks, BN/64 rounds of 512 ----
#pragma unroll
        for (int m = 0; m < BN / 64; m++) {
            int unit = m * 512 + tid;
            int r = unit >> 3, pc = unit & 7;
            int lc = pc ^ (r & 7);
            gload16(&Whi[(size_t)r * K + k0 + lc * 8], &Bh[(size_t)unit * 8]);
        }
        __syncthreads();   // drains vmcnt + lgkmcnt

        const int lo4 = l & 15;
        const int swz = l & 7;
#pragma unroll
        for (int kh = 0; kh < BK; kh += 32) {
            int q = (kh >> 3) + (l >> 4);
            int ra = w * 16 + lo4;
            bf16x8 a = *(const bf16x8*)&As[ra * 64 + (q ^ swz) * 8];
#pragma unroll
            for (int j = 0; j < NJ; j++) {
                int rb = j * 16 + lo4;
                bf16x8 bh = *(const bf16x8*)&Bh[rb * 64 + (q ^ swz) * 8];
                acc[j] = __builtin_amdgcn_mfma_f32_16x16x32_bf16(a, bh, acc[j], 0, 0, 0);
            }
        }
        __syncthreads();
    }

    float dnv[4];
#pragma unroll
    for (int r = 0; r < 4; r++) {
        int row = row0 + w * 16 + (l >> 4) * 4 + r;
        dnv[r] = (row < n) ? dinv[row] : 0.f;
    }
    const int cb = l & 15;
    if (MODE == 0) {
        // fp8 pack: lane packs (col cb, col cb+16) of slice s -> bytes (2cb, 2cb+1)
        uchar_t* C8 = (uchar_t*)Cv;
#pragma unroll
        for (int s = 0; s < NJ / 2; s++) {
#pragma unroll
            for (int r = 0; r < 4; r++) {
                int row = row0 + w * 16 + (l >> 4) * 4 + r;
                if (row < n) {
                    ushort_t pk = pk2fp8(dnv[r] * acc[2 * s][r], dnv[r] * acc[2 * s + 1][r]);
                    *(ushort_t*)&C8[(size_t)s * n * 32 + (size_t)row * 32 + cb * 2] = pk;
                }
            }
        }
    } else {
        ushort_t* C = (ushort_t*)Cv;
#pragma unroll
        for (int j = 0; j < NJ; j++) {
#pragma unroll
            for (int r = 0; r < 4; r++) {
                int row = row0 + w * 16 + (l >> 4) * 4 + r;
                if (row < n)
                    C[(size_t)row * OST + j * 16 + cb] = f2bf(dnv[r] * acc[j][r]);
            }
        }
    }
}

// ---------------- sliced aggregation (layers 1,2) — fp8 32B rows, L2-fit ----
// block=(bucket,slice); slice=blk&3; h8 [4][N][32] fp8 (phys byte order)
// 2 lanes/node x uint4 (16 fp8 feats); out bf16 [4][N][32] in SAME phys order

__global__ __launch_bounds__(256) void k_agg_slice(const uint_t* __restrict__ colsort,
                                                   const int* __restrict__ rp,
                                                   const uchar_t* __restrict__ h8,
                                                   const float* __restrict__ dinv,
                                                   const float* __restrict__ bias,
                                                   ushort_t* __restrict__ out, int N) {
    __shared__ int srp[BNODES + 1];
    __shared__ uint_t cols[BCAP];
    int blk = blockIdx.x;
    int slice = blk & 3, b = blk >> 2;
    int tid = threadIdx.x;
    if (tid <= BNODES) srp[tid] = rp[b * (BNODES + 1) + tid];
    __syncthreads();
    int cnt = srp[BNODES];
    for (int e = tid; e < cnt; e += 256) cols[e] = colsort[(size_t)b * BCAP + e];
    __syncthreads();
    int fh = tid & 1;                  // 16B half of the 32B row (16 fp8 feats)
    int nl = tid >> 1;                 // node slot 0..127
    int n = b * BNODES + nl;
    if (n >= N) return;
    const uchar_t* hs = &h8[(size_t)slice * N * 32 + fh * 16];
    // bias for phys slot p = fh*16+i : logical c = (p&1)*16 + (p>>1)
    float bv[16];
#pragma unroll
    for (int i = 0; i < 16; i++) {
        int p = fh * 16 + i;
        bv[i] = bias[slice * 32 + ((p & 1) << 4) + (p >> 1)];
    }
    int e = srp[nl], e1 = srp[nl + 1];
    f32x2 a2[8];
    {
        uint4 sv = *(const uint4*)&hs[(size_t)n * 32];
        a2[0] = unpk_lo(sv.x); a2[1] = unpk_hi(sv.x);
        a2[2] = unpk_lo(sv.y); a2[3] = unpk_hi(sv.y);
        a2[4] = unpk_lo(sv.z); a2[5] = unpk_hi(sv.z);
        a2[6] = unpk_lo(sv.w); a2[7] = unpk_hi(sv.w);
    }
    for (; e + 4 <= e1; e += 4) {
        uint4 v[4];
#pragma unroll
        for (int i = 0; i < 4; i++) v[i] = *(const uint4*)&hs[(size_t)cols[e + i] * 32];
#pragma unroll
        for (int i = 0; i < 4; i++) {
            a2[0] += unpk_lo(v[i].x); a2[1] += unpk_hi(v[i].x);
            a2[2] += unpk_lo(v[i].y); a2[3] += unpk_hi(v[i].y);
            a2[4] += unpk_lo(v[i].z); a2[5] += unpk_hi(v[i].z);
            a2[6] += unpk_lo(v[i].w); a2[7] += unpk_hi(v[i].w);
        }
    }
    for (; e < e1; e++) {
        uint4 v = *(const uint4*)&hs[(size_t)cols[e] * 32];
        a2[0] += unpk_lo(v.x); a2[1] += unpk_hi(v.x);
        a2[2] += unpk_lo(v.y); a2[3] += unpk_hi(v.y);
        a2[4] += unpk_lo(v.z); a2[5] += unpk_hi(v.z);
        a2[6] += unpk_lo(v.w); a2[7] += unpk_hi(v.w);
    }
    float dn = dinv[n];
    uint_t o[8];
#pragma unroll
    for (int k = 0; k < 8; k++) {
        float r0 = fmaxf(fmaf(dn, a2[k].x, bv[2 * k]),     0.f);
        float r1 = fmaxf(fmaf(dn, a2[k].y, bv[2 * k + 1]), 0.f);
        o[k] = ((uint_t)f2bf(r1) << 16) | f2bf(r0);
    }
    ushort_t* op = &out[((size_t)slice * N + n) * 32 + fh * 16];
    *(uint4*)&op[0] = make_uint4(o[0], o[1], o[2], o[3]);
    *(uint4*)&op[8] = make_uint4(o[4], o[5], o[6], o[7]);
}

// ---------------- layer-3 aggregation + log_softmax — padded 128B rows ------
// h3 row-major [N][64] bf16 pre-scaled (cols >= 40 junk, never read)

__global__ __launch_bounds__(256) void k_agg40_lsm(const uint_t* __restrict__ colsort,
                                                   const int* __restrict__ rp,
                                                   const ushort_t* __restrict__ h3,
                                                   const float* __restrict__ dinv,
                                                   const float* __restrict__ bias,
                                                   float* __restrict__ out, int N) {
    __shared__ int srp[BNODES + 1];
    __shared__ uint_t cols[BCAP];
    int b = blockIdx.x, tid = threadIdx.x;
    if (tid <= BNODES) srp[tid] = rp[b * (BNODES + 1) + tid];
    __syncthreads();
    int cnt = srp[BNODES];
    for (int e = tid; e < cnt; e += 256) cols[e] = colsort[(size_t)b * BCAP + e];
    __syncthreads();
    int fo = tid & 7;                  // feature octant (8 feats, 16B)
    int g  = tid >> 3;                 // node slot 0..31
    bool act = fo < 5;
    float bv[8];
#pragma unroll
    for (int j = 0; j < 8; j++) bv[j] = act ? bias[fo * 8 + j] : 0.f;
    for (int nl = g; nl < BNODES; nl += 32) {
        int n = b * BNODES + nl;
        if (n >= N) break;
        int e = srp[nl], e1 = srp[nl + 1];
        float a[8] = {0.f, 0.f, 0.f, 0.f, 0.f, 0.f, 0.f, 0.f};
        if (act) {
            uint4 sv = *(const uint4*)&h3[(size_t)n * 64 + fo * 8];
            a[0] = lo2f(sv.x); a[1] = hi2f(sv.x); a[2] = lo2f(sv.y); a[3] = hi2f(sv.y);
            a[4] = lo2f(sv.z); a[5] = hi2f(sv.z); a[6] = lo2f(sv.w); a[7] = hi2f(sv.w);
        }
        for (; e + 4 <= e1; e += 4) {
            if (act) {
                uint4 v[4];
#pragma unroll
                for (int i = 0; i < 4; i++) v[i] = *(const uint4*)&h3[(size_t)cols[e + i] * 64 + fo * 8];
#pragma unroll
                for (int i = 0; i < 4; i++) {
                    a[0] = dot2bf(v[i].x, LOMASK, a[0]); a[1] = dot2bf(v[i].x, HIMASK, a[1]);
                    a[2] = dot2bf(v[i].y, LOMASK, a[2]); a[3] = dot2bf(v[i].y, HIMASK, a[3]);
                    a[4] = dot2bf(v[i].z, LOMASK, a[4]); a[5] = dot2bf(v[i].z, HIMASK, a[5]);
                    a[6] = dot2bf(v[i].w, LOMASK, a[6]); a[7] = dot2bf(v[i].w, HIMASK, a[7]);
                }
            }
        }
        for (; e < e1; e++) {
            if (act) {
                uint4 v = *(const uint4*)&h3[(size_t)cols[e] * 64 + fo * 8];
                a[0] = dot2bf(v.x, LOMASK, a[0]); a[1] = dot2bf(v.x, HIMASK, a[1]);
                a[2] = dot2bf(v.y, LOMASK, a[2]); a[3] = dot2bf(v.y, HIMASK, a[3]);
                a[4] = dot2bf(v.z, LOMASK, a[4]); a[5] = dot2bf(v.z, HIMASK, a[5]);
                a[6] = dot2bf(v.w, LOMASK, a[6]); a[7] = dot2bf(v.w, HIMASK, a[7]);
            }
        }
        float dn = dinv[n];
        float z[8];
        float m = -INFINITY;
#pragma unroll
        for (int j = 0; j < 8; j++) {
            z[j] = act ? fmaf(dn, a[j], bv[j]) : -INFINITY;
            m = fmaxf(m, z[j]);
        }
#pragma unroll
        for (int off = 4; off; off >>= 1) m = fmaxf(m, __shfl_xor(m, off, 8));
        float p = 0.f;
        if (act) {
#pragma unroll
            for (int j = 0; j < 8; j++) p += expf(z[j] - m);
        }
#pragma unroll
        for (int off = 4; off; off >>= 1) p += __shfl_xor(p, off, 8);
        float lse = m + logf(p);
        if (act) {
            float4 o0 = make_float4(z[0] - lse, z[1] - lse, z[2] - lse, z[3] - lse);
            float4 o1 = make_float4(z[4] - lse, z[5] - lse, z[6] - lse, z[7] - lse);
            *(float4*)&out[(size_t)n * NCLASS + fo * 8]     = o0;
            *(float4*)&out[(size_t)n * NCLASS + fo * 8 + 4] = o1;
        }
    }
}

// ---------------- launch ----------------

extern "C" void kernel_launch(void* const* d_in, const int* in_sizes, int n_in,
                              void* d_out, int out_size, void* d_ws, size_t ws_size,
                              hipStream_t stream) {
    const float* x  = (const float*)d_in[0];
    const int*   ei = (const int*)d_in[1];
    const float* W1 = (const float*)d_in[2];
    const float* b1 = (const float*)d_in[3];
    const float* W2 = (const float*)d_in[4];
    const float* b2 = (const float*)d_in[5];
    const float* W3 = (const float*)d_in[6];
    const float* b3 = (const float*)d_in[7];
    float* out = (float*)d_out;
    const int N = in_sizes[0] / NFEAT;
    const int E = in_sizes[1] / 2;
    const int* src = ei;
    const int* dst = ei + E;
    const int NBK = (N + BNODES - 1) / BNODES;
    const int NBLK_E = (E + EPB - 1) / EPB;

    char* ws = (char*)d_ws;
    size_t off = 0;
    auto alloc = [&](size_t bytes) -> void* {
        void* p = ws + off;
        off += (bytes + 255) & ~(size_t)255;
        return p;
    };
    int*      bcnt    = (int*)alloc((size_t)NBK * 4);
    int*      ecnt    = (int*)alloc((size_t)NBK * NBLK_E * 4);
    uint_t*   bstore  = (uint_t*)alloc((size_t)NBK * BCAP * 4);
    uint_t*   colsort = (uint_t*)alloc((size_t)NBK * BCAP * 4);
    int*      rp      = (int*)alloc((size_t)NBK * (BNODES + 1) * 4);
    float*    dinv    = (float*)alloc((size_t)N * 4);
    uchar_t*  h8      = (uchar_t*)alloc((size_t)N * NHID);       // fp8 GEMM out [4][N][32]
    ushort_t* abuf    = (ushort_t*)alloc((size_t)N * NHID * 2);  // bf16 agg out (phys order)
    ushort_t* h3      = (ushort_t*)alloc((size_t)N * 64 * 2);    // padded [N][64] bf16
    ushort_t* Whi1    = (ushort_t*)alloc((size_t)NHID * NFEAT * 2);
    ushort_t* Whi2    = (ushort_t*)alloc((size_t)NHID * NHID * 2);
    ushort_t* Whi3    = (ushort_t*)alloc((size_t)64 * NHID * 2);
    (void)ws_size; (void)n_in; (void)out_size;

    // fused weight prep (T2/T3 k-permuted to match fp8 byte-pair order)
    int wtelems = NHID * NFEAT + NHID * NHID + 64 * NHID;
    k_wtall<<<(wtelems + 255) / 256, 256, 0, stream>>>(W1, W2, W3, Whi1, Whi2, Whi3);

    // edge partition (no global atomics) + per-bucket sort + dinv
    k_ehist<<<NBLK_E, 256, 0, stream>>>(dst, ecnt, E, NBK, NBLK_E);
    k_escan<<<NBK, 128, 0, stream>>>(ecnt, bcnt, NBLK_E);
    k_escatter<<<NBLK_E, 256, 0, stream>>>(src, dst, ecnt, bstore, E, NBK, NBLK_E);
    k_bsort<<<NBK, 256, 0, stream>>>(bstore, bcnt, colsort, rp, dinv, N);

    int ngemm = (N + 127) / 128;
    // layer 1
    k_gemm_mfma<NFEAT, true, 128, 0, 0><<<ngemm, 512, 0, stream>>>(x, Whi1, dinv, h8, N);
    k_agg_slice<<<NBK * 4, 256, 0, stream>>>(colsort, rp, h8, dinv, b1, abuf, N);
    // layer 2
    k_gemm_mfma<NHID, false, 128, 0, 0><<<ngemm, 512, 0, stream>>>(abuf, Whi2, dinv, h8, N);
    k_agg_slice<<<NBK * 4, 256, 0, stream>>>(colsort, rp, h8, dinv, b2, abuf, N);
    // layer 3 + log_softmax
    k_gemm_mfma<NHID, false, 64, 64, 1><<<ngemm, 512, 0, stream>>>(abuf, Whi3, dinv, h3, N);
    k_agg40_lsm<<<NBK, 256, 0, stream>>>(colsort, rp, h3, dinv, b3, out, N);
}

// Round 17
// 238.390 us; speedup vs baseline: 1.3898x; 1.0227x over previous
//
#include <hip/hip_runtime.h>
#include <math.h>

#define NFEAT 256
#define NHID 128
#define NCLASS 40
#define BNODES 128
#define BSHIFT 7
#define BCAP 2688
#define MAXBK 1024
#define EPB 16384

typedef unsigned short ushort_t;
typedef unsigned int uint_t;
typedef unsigned char uchar_t;
typedef __attribute__((ext_vector_type(8))) short bf16x8;
typedef __attribute__((ext_vector_type(4))) float f32x4;
typedef __attribute__((ext_vector_type(2))) float f32x2;

static __device__ inline float bf2f(ushort_t u) {
    union { uint_t u; float f; } v; v.u = (uint_t)u << 16; return v.f;
}
static __device__ inline float lo2f(uint_t u) {
    union { uint_t u; float f; } v; v.u = u << 16; return v.f;
}
static __device__ inline float hi2f(uint_t u) {
    union { uint_t u; float f; } v; v.u = u & 0xFFFF0000u; return v.f;
}
static __device__ inline ushort_t f2bf(float f) {
    uint_t u = __float_as_uint(f);
    u += 0x7FFF + ((u >> 16) & 1);           // round-to-nearest-even
    return (ushort_t)(u >> 16);
}
// fused bf16-extract + fp32 accumulate
static __device__ inline float dot2bf(uint_t pk, uint_t mask, float c) {
    float r;
    asm("v_dot2_f32_bf16 %0, %1, %2, %3" : "=v"(r) : "v"(pk), "v"(mask), "v"(c));
    return r;
}
#define LOMASK 0x00003F80u
#define HIMASK 0x3F800000u

// async global->LDS 16B (dest = wave-uniform base + lane*16)
static __device__ __forceinline__ void gload16(const void* g, void* l) {
    __builtin_amdgcn_global_load_lds(
        (const __attribute__((address_space(1))) uint_t*)g,
        (__attribute__((address_space(3))) uint_t*)l, 16, 0, 0);
}

// fp8 e4m3 pack/unpack (gfx950 native)
static __device__ inline ushort_t pk2fp8(float a, float b) {
    return (ushort_t)__builtin_amdgcn_cvt_pk_fp8_f32(a, b, 0, false);
}
static __device__ inline f32x2 unpk_lo(uint_t w) {
    return __builtin_amdgcn_cvt_pk_f32_fp8(w, false);
}
static __device__ inline f32x2 unpk_hi(uint_t w) {
    return __builtin_amdgcn_cvt_pk_f32_fp8(w, true);
}

// ---------------- edge partition by dst-bucket: hist / scan / scatter --------

__global__ __launch_bounds__(256) void k_ehist(const int* __restrict__ dst,
                                               int* __restrict__ cnt,
                                               int E, int nbk, int nblk) {
    __shared__ int hist[MAXBK];
    int tid = threadIdx.x, be = blockIdx.x;
    for (int i = tid; i < nbk; i += 256) hist[i] = 0;
    __syncthreads();
    int e0 = be * EPB, e1 = min(e0 + EPB, E);
    for (int e = e0 + tid; e < e1; e += 256)
        atomicAdd(&hist[dst[e] >> BSHIFT], 1);          // LDS int atomic: native
    __syncthreads();
    for (int i = tid; i < nbk; i += 256)
        cnt[(size_t)i * nblk + be] = hist[i];
}

__global__ __launch_bounds__(128) void k_escan(int* __restrict__ cnt,
                                               int* __restrict__ bcnt, int nblk) {
    __shared__ int buf[128];
    int b = blockIdx.x, tid = threadIdx.x;
    int v = (tid < nblk) ? cnt[(size_t)b * nblk + tid] : 0;
    buf[tid] = v;
    __syncthreads();
    for (int off = 1; off < 128; off <<= 1) {
        int t = (tid >= off) ? buf[tid - off] : 0;
        __syncthreads();
        buf[tid] += t;
        __syncthreads();
    }
    if (tid < nblk) cnt[(size_t)b * nblk + tid] = buf[tid] - v;   // exclusive
    if (tid == 127) bcnt[b] = buf[127];                           // total
}

__global__ __launch_bounds__(256) void k_escatter(const int* __restrict__ src,
                                                  const int* __restrict__ dst,
                                                  const int* __restrict__ cnt,
                                                  uint_t* __restrict__ bstore,
                                                  int E, int nbk, int nblk) {
    __shared__ int cur[MAXBK];
    int tid = threadIdx.x, be = blockIdx.x;
    for (int i = tid; i < nbk; i += 256)
        cur[i] = cnt[(size_t)i * nblk + be];
    __syncthreads();
    int e0 = be * EPB, e1 = min(e0 + EPB, E);
    for (int e = e0 + tid; e < e1; e += 256) {
        int d = dst[e];
        int b = d >> BSHIFT;
        int p = atomicAdd(&cur[b], 1);                  // LDS int atomic: native
        if (p < BCAP)
            bstore[(size_t)b * BCAP + p] = ((uint_t)(d & (BNODES - 1)) << 20) | (uint_t)src[e];
    }
}

// ---------------- per-bucket counting sort (LDS), + rp + dinv ----------------

__global__ __launch_bounds__(256) void k_bsort(const uint_t* __restrict__ bstore,
                                               const int* __restrict__ bcnt,
                                               uint_t* __restrict__ colsort,
                                               int* __restrict__ rp,
                                               float* __restrict__ dinv, int N) {
    __shared__ uint_t rec[BCAP];
    __shared__ uint_t srt[BCAP];
    __shared__ int hist[BNODES];
    __shared__ int scan[BNODES];
    __shared__ int cur[BNODES];
    int b = blockIdx.x, tid = threadIdx.x;
    if (tid < BNODES) hist[tid] = 0;
    __syncthreads();
    int cnt = min(bcnt[b], BCAP);
    const uint_t* gp = &bstore[(size_t)b * BCAP];
    for (int e = tid; e < cnt; e += 256) {
        uint_t r = gp[e];
        rec[e] = r;
        atomicAdd(&hist[r >> 20], 1);          // int LDS atomic: native
    }
    __syncthreads();
    if (tid < BNODES) scan[tid] = hist[tid];
    __syncthreads();
    for (int off = 1; off < BNODES; off <<= 1) {
        int v = 0;
        if (tid < BNODES && tid >= off) v = scan[tid - off];
        __syncthreads();
        if (tid < BNODES) scan[tid] += v;
        __syncthreads();
    }
    if (tid < BNODES) cur[tid] = scan[tid] - hist[tid];   // exclusive
    __syncthreads();
    for (int e = tid; e < cnt; e += 256) {
        uint_t r = rec[e];
        int p = atomicAdd(&cur[r >> 20], 1);   // int LDS atomic: native
        srt[p] = r & 0xFFFFF;
    }
    __syncthreads();
    uint_t* cs = &colsort[(size_t)b * BCAP];
    for (int e = tid; e < cnt; e += 256) cs[e] = srt[e];
    if (tid < BNODES) {
        rp[b * (BNODES + 1) + tid] = scan[tid] - hist[tid];
        int n = b * BNODES + tid;
        if (n < N) dinv[n] = rsqrtf((float)hist[tid] + 1.0f);
    }
    if (tid == 0) rp[b * (BNODES + 1) + BNODES] = cnt;
}

// ---------------- fused weight transpose -> bf16 -----------------------------
// T2,T3 rows permuted on k: phys kp -> logical k = (kp>>5)*32 + ((kp&1)<<4) + ((kp&31)>>1)
// (matches fp8 byte-pair pack of the previous layer; unchanged by 64B grouping)

__global__ __launch_bounds__(256) void k_wtall(const float* __restrict__ W1,
                                               const float* __restrict__ W2,
                                               const float* __restrict__ W3,
                                               ushort_t* __restrict__ T1,
                                               ushort_t* __restrict__ T2,
                                               ushort_t* __restrict__ T3) {
    int idx = blockIdx.x * 256 + threadIdx.x;
    if (idx < NHID * NFEAT) {                                // T1[128][256] (no perm)
        int nrow = idx >> 8, k = idx & 255;
        T1[idx] = f2bf(W1[(size_t)k * NHID + nrow]);
    } else if ((idx -= NHID * NFEAT) < NHID * NHID) {        // T2[128][128] k-perm
        int nrow = idx >> 7, kp = idx & 127;
        int s = kp >> 5, pl = kp & 31;
        int k = s * 32 + ((pl & 1) << 4) + (pl >> 1);
        T2[idx] = f2bf(W2[(size_t)k * NHID + nrow]);
    } else if ((idx -= NHID * NHID) < 64 * NHID) {           // T3[64][128] k-perm, pad
        int nrow = idx >> 7, kp = idx & 127;
        int s = kp >> 5, pl = kp & 31;
        int k = s * 32 + ((pl & 1) << 4) + (pl >> 1);
        T3[idx] = f2bf(nrow < NCLASS ? W3[(size_t)k * NCLASS + nrow] : 0.f);
    }
}

// ---------------- MFMA GEMM (bf16 weights, BM=128, 512 thr / 8 waves) -------
// C = (A @ W) * dinv[row]   (pre-scaled h')
// MODE 0: out fp8 e4m3, slice-major [2][N][64] (64B rows), byte-pair packed
// MODE 1: out bf16 row-major [N][OST]
// A_FP32: A row-major fp32 (convert path); else A bf16 phys-order [2][N][64]

template<int K, bool A_FP32, int BN, int OST, int MODE>
__global__ __launch_bounds__(512) void k_gemm_mfma(const void* __restrict__ Ap,
                                                   const ushort_t* __restrict__ Whi,
                                                   const float* __restrict__ dinv,
                                                   void* __restrict__ Cv, int n) {
    const int BM = 128, BK = 64;
    __shared__ ushort_t As[BM * BK];
    __shared__ ushort_t Bh[BN * BK];
    const int tid = threadIdx.x;
    const int w = tid >> 6, l = tid & 63;
    const int row0 = blockIdx.x * BM;
    const int NJ = BN / 16;
    f32x4 acc[NJ] = {};

    for (int k0 = 0; k0 < K; k0 += BK) {
        // ---- stage A tile (128 x 64) ----
        if (A_FP32) {
            int r = tid >> 2;                       // 0..127
            if (row0 + r < n) {
                const float* A = (const float*)Ap;
                const float* ap = &A[(size_t)(row0 + r) * K + k0];
#pragma unroll
                for (int h = 0; h < 2; h++) {
                    int q = (tid & 3) * 2 + h;
                    float4 v0 = *(const float4*)&ap[q * 8];
                    float4 v1 = *(const float4*)&ap[q * 8 + 4];
                    ushort4 o0, o1;
                    o0.x = f2bf(v0.x); o0.y = f2bf(v0.y); o0.z = f2bf(v0.z); o0.w = f2bf(v0.w);
                    o1.x = f2bf(v1.x); o1.y = f2bf(v1.y); o1.z = f2bf(v1.z); o1.w = f2bf(v1.w);
                    int pc = q ^ (r & 7);
                    *(ushort4*)&As[r * 64 + pc * 8]     = o0;
                    *(ushort4*)&As[r * 64 + pc * 8 + 4] = o1;
                }
            }
        } else {
            const ushort_t* A = (const ushort_t*)Ap;
#pragma unroll
            for (int m = 0; m < 2; m++) {           // 1024 chunks, 2 rounds of 512
                int unit = m * 512 + tid;
                int r = unit >> 3, pc = unit & 7;
                int lc = pc ^ (r & 7);
                int kk = k0 + lc * 8;
                size_t rowg = (size_t)min(row0 + r, n - 1);   // clamp: junk rows unused
                const ushort_t* srcp = &A[(size_t)(kk >> 6) * n * 64 + rowg * 64 + (kk & 63)];
                gload16(srcp, &As[(size_t)unit * 8]);
            }
        }
        // ---- stage B tile (BN x 64): BN*8 chunks, BN/64 rounds of 512 ----
#pragma unroll
        for (int m = 0; m < BN / 64; m++) {
            int unit = m * 512 + tid;
            int r = unit >> 3, pc = unit & 7;
            int lc = pc ^ (r & 7);
            gload16(&Whi[(size_t)r * K + k0 + lc * 8], &Bh[(size_t)unit * 8]);
        }
        __syncthreads();   // drains vmcnt + lgkmcnt

        const int lo4 = l & 15;
        const int swz = l & 7;
#pragma unroll
        for (int kh = 0; kh < BK; kh += 32) {
            int q = (kh >> 3) + (l >> 4);
            int ra = w * 16 + lo4;
            bf16x8 a = *(const bf16x8*)&As[ra * 64 + (q ^ swz) * 8];
#pragma unroll
            for (int j = 0; j < NJ; j++) {
                int rb = j * 16 + lo4;
                bf16x8 bh = *(const bf16x8*)&Bh[rb * 64 + (q ^ swz) * 8];
                acc[j] = __builtin_amdgcn_mfma_f32_16x16x32_bf16(a, bh, acc[j], 0, 0, 0);
            }
        }
        __syncthreads();
    }

    float dnv[4];
#pragma unroll
    for (int r = 0; r < 4; r++) {
        int row = row0 + w * 16 + (l >> 4) * 4 + r;
        dnv[r] = (row < n) ? dinv[row] : 0.f;
    }
    const int cb = l & 15;
    if (MODE == 0) {
        // fp8 pack: old slice s = 2t+sub -> row t, bytes sub*32 + {2cb, 2cb+1}
        uchar_t* C8 = (uchar_t*)Cv;
#pragma unroll
        for (int s = 0; s < NJ / 2; s++) {
            int t = s >> 1, sub = s & 1;
#pragma unroll
            for (int r = 0; r < 4; r++) {
                int row = row0 + w * 16 + (l >> 4) * 4 + r;
                if (row < n) {
                    ushort_t pk = pk2fp8(dnv[r] * acc[2 * s][r], dnv[r] * acc[2 * s + 1][r]);
                    *(ushort_t*)&C8[(size_t)t * n * 64 + (size_t)row * 64 + sub * 32 + cb * 2] = pk;
                }
            }
        }
    } else {
        ushort_t* C = (ushort_t*)Cv;
#pragma unroll
        for (int j = 0; j < NJ; j++) {
#pragma unroll
            for (int r = 0; r < 4; r++) {
                int row = row0 + w * 16 + (l >> 4) * 4 + r;
                if (row < n)
                    C[(size_t)row * OST + j * 16 + cb] = f2bf(dnv[r] * acc[j][r]);
            }
        }
    }
}

// ---------------- sliced aggregation (layers 1,2) — fp8 64B line rows -------
// block=(bucket,slice); slice=blk&1; h8 [2][N][64] fp8 (phys byte order)
// 4 lanes/node x uint4 = full 64B line; out bf16 [2][N][64] same phys order

__global__ __launch_bounds__(256) void k_agg_slice(const uint_t* __restrict__ colsort,
                                                   const int* __restrict__ rp,
                                                   const uchar_t* __restrict__ h8,
                                                   const float* __restrict__ dinv,
                                                   const float* __restrict__ bias,
                                                   ushort_t* __restrict__ out, int N) {
    __shared__ int srp[BNODES + 1];
    __shared__ uint_t cols[BCAP];
    int blk = blockIdx.x;
    int slice = blk & 1, b = blk >> 1;
    int tid = threadIdx.x;
    if (tid <= BNODES) srp[tid] = rp[b * (BNODES + 1) + tid];
    __syncthreads();
    int cnt = srp[BNODES];
    for (int e = tid; e < cnt; e += 256) cols[e] = colsort[(size_t)b * BCAP + e];
    __syncthreads();
    int fq = tid & 3;                  // 16B quarter of the 64B row (16 fp8 feats)
    int q  = tid >> 2;                 // node slot 0..63
    const uchar_t* hs = &h8[(size_t)slice * N * 64 + fq * 16];
    // bias for phys byte p = fq*16+i : s = 2*slice + (p>>5), pl = p&31,
    // logical c = s*32 + ((pl&1)<<4) + (pl>>1)
    float bv[16];
#pragma unroll
    for (int i = 0; i < 16; i++) {
        int p = fq * 16 + i;
        int s = 2 * slice + (p >> 5), pl = p & 31;
        bv[i] = bias[s * 32 + ((pl & 1) << 4) + (pl >> 1)];
    }
    for (int nl = q; nl < BNODES; nl += 64) {
        int n = b * BNODES + nl;
        if (n >= N) break;
        int e = srp[nl], e1 = srp[nl + 1];
        f32x2 a2[8];
        {
            uint4 sv = *(const uint4*)&hs[(size_t)n * 64];
            a2[0] = unpk_lo(sv.x); a2[1] = unpk_hi(sv.x);
            a2[2] = unpk_lo(sv.y); a2[3] = unpk_hi(sv.y);
            a2[4] = unpk_lo(sv.z); a2[5] = unpk_hi(sv.z);
            a2[6] = unpk_lo(sv.w); a2[7] = unpk_hi(sv.w);
        }
        for (; e + 4 <= e1; e += 4) {
            uint4 v[4];
#pragma unroll
            for (int i = 0; i < 4; i++) v[i] = *(const uint4*)&hs[(size_t)cols[e + i] * 64];
#pragma unroll
            for (int i = 0; i < 4; i++) {
                a2[0] += unpk_lo(v[i].x); a2[1] += unpk_hi(v[i].x);
                a2[2] += unpk_lo(v[i].y); a2[3] += unpk_hi(v[i].y);
                a2[4] += unpk_lo(v[i].z); a2[5] += unpk_hi(v[i].z);
                a2[6] += unpk_lo(v[i].w); a2[7] += unpk_hi(v[i].w);
            }
        }
        for (; e < e1; e++) {
            uint4 v = *(const uint4*)&hs[(size_t)cols[e] * 64];
            a2[0] += unpk_lo(v.x); a2[1] += unpk_hi(v.x);
            a2[2] += unpk_lo(v.y); a2[3] += unpk_hi(v.y);
            a2[4] += unpk_lo(v.z); a2[5] += unpk_hi(v.z);
            a2[6] += unpk_lo(v.w); a2[7] += unpk_hi(v.w);
        }
        float dn = dinv[n];
        uint_t o[8];
#pragma unroll
        for (int k = 0; k < 8; k++) {
            float r0 = fmaxf(fmaf(dn, a2[k].x, bv[2 * k]),     0.f);
            float r1 = fmaxf(fmaf(dn, a2[k].y, bv[2 * k + 1]), 0.f);
            o[k] = ((uint_t)f2bf(r1) << 16) | f2bf(r0);
        }
        ushort_t* op = &out[((size_t)slice * N + n) * 64 + fq * 16];
        *(uint4*)&op[0] = make_uint4(o[0], o[1], o[2], o[3]);
        *(uint4*)&op[8] = make_uint4(o[4], o[5], o[6], o[7]);
    }
}

// ---------------- layer-3 aggregation + log_softmax — padded 128B rows ------
// h3 row-major [N][64] bf16 pre-scaled (cols >= 40 junk, never read)

__global__ __launch_bounds__(256) void k_agg40_lsm(const uint_t* __restrict__ colsort,
                                                   const int* __restrict__ rp,
                                                   const ushort_t* __restrict__ h3,
                                                   const float* __restrict__ dinv,
                                                   const float* __restrict__ bias,
                                                   float* __restrict__ out, int N) {
    __shared__ int srp[BNODES + 1];
    __shared__ uint_t cols[BCAP];
    int b = blockIdx.x, tid = threadIdx.x;
    if (tid <= BNODES) srp[tid] = rp[b * (BNODES + 1) + tid];
    __syncthreads();
    int cnt = srp[BNODES];
    for (int e = tid; e < cnt; e += 256) cols[e] = colsort[(size_t)b * BCAP + e];
    __syncthreads();
    int fo = tid & 7;                  // feature octant (8 feats, 16B)
    int g  = tid >> 3;                 // node slot 0..31
    bool act = fo < 5;
    float bv[8];
#pragma unroll
    for (int j = 0; j < 8; j++) bv[j] = act ? bias[fo * 8 + j] : 0.f;
    for (int nl = g; nl < BNODES; nl += 32) {
        int n = b * BNODES + nl;
        if (n >= N) break;
        int e = srp[nl], e1 = srp[nl + 1];
        float a[8] = {0.f, 0.f, 0.f, 0.f, 0.f, 0.f, 0.f, 0.f};
        if (act) {
            uint4 sv = *(const uint4*)&h3[(size_t)n * 64 + fo * 8];
            a[0] = lo2f(sv.x); a[1] = hi2f(sv.x); a[2] = lo2f(sv.y); a[3] = hi2f(sv.y);
            a[4] = lo2f(sv.z); a[5] = hi2f(sv.z); a[6] = lo2f(sv.w); a[7] = hi2f(sv.w);
        }
        for (; e + 4 <= e1; e += 4) {
            if (act) {
                uint4 v[4];
#pragma unroll
                for (int i = 0; i < 4; i++) v[i] = *(const uint4*)&h3[(size_t)cols[e + i] * 64 + fo * 8];
#pragma unroll
                for (int i = 0; i < 4; i++) {
                    a[0] = dot2bf(v[i].x, LOMASK, a[0]); a[1] = dot2bf(v[i].x, HIMASK, a[1]);
                    a[2] = dot2bf(v[i].y, LOMASK, a[2]); a[3] = dot2bf(v[i].y, HIMASK, a[3]);
                    a[4] = dot2bf(v[i].z, LOMASK, a[4]); a[5] = dot2bf(v[i].z, HIMASK, a[5]);
                    a[6] = dot2bf(v[i].w, LOMASK, a[6]); a[7] = dot2bf(v[i].w, HIMASK, a[7]);
                }
            }
        }
        for (; e < e1; e++) {
            if (act) {
                uint4 v = *(const uint4*)&h3[(size_t)cols[e] * 64 + fo * 8];
                a[0] = dot2bf(v.x, LOMASK, a[0]); a[1] = dot2bf(v.x, HIMASK, a[1]);
                a[2] = dot2bf(v.y, LOMASK, a[2]); a[3] = dot2bf(v.y, HIMASK, a[3]);
                a[4] = dot2bf(v.z, LOMASK, a[4]); a[5] = dot2bf(v.z, HIMASK, a[5]);
                a[6] = dot2bf(v.w, LOMASK, a[6]); a[7] = dot2bf(v.w, HIMASK, a[7]);
            }
        }
        float dn = dinv[n];
        float z[8];
        float m = -INFINITY;
#pragma unroll
        for (int j = 0; j < 8; j++) {
            z[j] = act ? fmaf(dn, a[j], bv[j]) : -INFINITY;
            m = fmaxf(m, z[j]);
        }
#pragma unroll
        for (int off = 4; off; off >>= 1) m = fmaxf(m, __shfl_xor(m, off, 8));
        float p = 0.f;
        if (act) {
#pragma unroll
            for (int j = 0; j < 8; j++) p += expf(z[j] - m);
        }
#pragma unroll
        for (int off = 4; off; off >>= 1) p += __shfl_xor(p, off, 8);
        float lse = m + logf(p);
        if (act) {
            float4 o0 = make_float4(z[0] - lse, z[1] - lse, z[2] - lse, z[3] - lse);
            float4 o1 = make_float4(z[4] - lse, z[5] - lse, z[6] - lse, z[7] - lse);
            *(float4*)&out[(size_t)n * NCLASS + fo * 8]     = o0;
            *(float4*)&out[(size_t)n * NCLASS + fo * 8 + 4] = o1;
        }
    }
}

// ---------------- launch ----------------

extern "C" void kernel_launch(void* const* d_in, const int* in_sizes, int n_in,
                              void* d_out, int out_size, void* d_ws, size_t ws_size,
                              hipStream_t stream) {
    const float* x  = (const float*)d_in[0];
    const int*   ei = (const int*)d_in[1];
    const float* W1 = (const float*)d_in[2];
    const float* b1 = (const float*)d_in[3];
    const float* W2 = (const float*)d_in[4];
    const float* b2 = (const float*)d_in[5];
    const float* W3 = (const float*)d_in[6];
    const float* b3 = (const float*)d_in[7];
    float* out = (float*)d_out;
    const int N = in_sizes[0] / NFEAT;
    const int E = in_sizes[1] / 2;
    const int* src = ei;
    const int* dst = ei + E;
    const int NBK = (N + BNODES - 1) / BNODES;
    const int NBLK_E = (E + EPB - 1) / EPB;

    char* ws = (char*)d_ws;
    size_t off = 0;
    auto alloc = [&](size_t bytes) -> void* {
        void* p = ws + off;
        off += (bytes + 255) & ~(size_t)255;
        return p;
    };
    int*      bcnt    = (int*)alloc((size_t)NBK * 4);
    int*      ecnt    = (int*)alloc((size_t)NBK * NBLK_E * 4);
    uint_t*   bstore  = (uint_t*)alloc((size_t)NBK * BCAP * 4);
    uint_t*   colsort = (uint_t*)alloc((size_t)NBK * BCAP * 4);
    int*      rp      = (int*)alloc((size_t)NBK * (BNODES + 1) * 4);
    float*    dinv    = (float*)alloc((size_t)N * 4);
    uchar_t*  h8      = (uchar_t*)alloc((size_t)N * NHID);       // fp8 GEMM out [2][N][64]
    ushort_t* abuf    = (ushort_t*)alloc((size_t)N * NHID * 2);  // bf16 agg out [2][N][64]
    ushort_t* h3      = (ushort_t*)alloc((size_t)N * 64 * 2);    // padded [N][64] bf16
    ushort_t* Whi1    = (ushort_t*)alloc((size_t)NHID * NFEAT * 2);
    ushort_t* Whi2    = (ushort_t*)alloc((size_t)NHID * NHID * 2);
    ushort_t* Whi3    = (ushort_t*)alloc((size_t)64 * NHID * 2);
    (void)ws_size; (void)n_in; (void)out_size;

    // fused weight prep (T2/T3 k-permuted to match fp8 byte-pair order)
    int wtelems = NHID * NFEAT + NHID * NHID + 64 * NHID;
    k_wtall<<<(wtelems + 255) / 256, 256, 0, stream>>>(W1, W2, W3, Whi1, Whi2, Whi3);

    // edge partition (no global atomics) + per-bucket sort + dinv
    k_ehist<<<NBLK_E, 256, 0, stream>>>(dst, ecnt, E, NBK, NBLK_E);
    k_escan<<<NBK, 128, 0, stream>>>(ecnt, bcnt, NBLK_E);
    k_escatter<<<NBLK_E, 256, 0, stream>>>(src, dst, ecnt, bstore, E, NBK, NBLK_E);
    k_bsort<<<NBK, 256, 0, stream>>>(bstore, bcnt, colsort, rp, dinv, N);

    int ngemm = (N + 127) / 128;
    // layer 1
    k_gemm_mfma<NFEAT, true, 128, 0, 0><<<ngemm, 512, 0, stream>>>(x, Whi1, dinv, h8, N);
    k_agg_slice<<<NBK * 2, 256, 0, stream>>>(colsort, rp, h8, dinv, b1, abuf, N);
    // layer 2
    k_gemm_mfma<NHID, false, 128, 0, 0><<<ngemm, 512, 0, stream>>>(abuf, Whi2, dinv, h8, N);
    k_agg_slice<<<NBK * 2, 256, 0, stream>>>(colsort, rp, h8, dinv, b2, abuf, N);
    // layer 3 + log_softmax
    k_gemm_mfma<NHID, false, 64, 64, 1><<<ngemm, 512, 0, stream>>>(abuf, Whi3, dinv, h3, N);
    k_agg40_lsm<<<NBK, 256, 0, stream>>>(colsort, rp, h3, dinv, b3, out, N);
}